// Round 10
// baseline (221.075 us; speedup 1.0000x reference)
//
#include <hip/hip_runtime.h>
#include <hip/hip_bf16.h>
#include <stdint.h>

#define S_LEN 2048
#define DIMSZ 2048
#define NH    16
#define HD    128
#define NQK   2176   // Q cols (2048) + K cols (128); V cols start here
#define NQKV  2304
#define NT    (S_LEN / 64)

typedef short  bf16x8  __attribute__((ext_vector_type(8)));
typedef float  floatx4 __attribute__((ext_vector_type(4)));
typedef float  floatx16 __attribute__((ext_vector_type(16)));
typedef int    intx4   __attribute__((ext_vector_type(4)));
typedef int    intx2   __attribute__((ext_vector_type(2)));
typedef unsigned short u16;

#define mfma32 __builtin_amdgcn_mfma_f32_32x32x16_bf16
#define LOG2E 1.4426950408889634f

// round-to-nearest-even f32 -> bf16 bits
__device__ __forceinline__ u16 f2bf(float x) {
  unsigned int u = __builtin_bit_cast(unsigned int, x);
  u = (u + 0x7FFFu + ((u >> 16) & 1u)) >> 16;
  return (u16)u;
}
__device__ __forceinline__ float bf2f(unsigned int bits) {
  return __builtin_bit_cast(float, bits << 16);
}

// v_cvt_pk_bf16_f32: word = (bf16(hi)<<16) | bf16(lo)   (plain VALU, no hazard)
__device__ __forceinline__ int cvtpk(float lo, float hi) {
  int r;
  asm("v_cvt_pk_bf16_f32 %0, %1, %2" : "=v"(r) : "v"(lo), "v"(hi));
  return r;
}

// 2^x — builtin so the compiler handles the TRANS wait-state hazard
#if __has_builtin(__builtin_amdgcn_exp2f)
__device__ __forceinline__ float fexp2(float x) { return __builtin_amdgcn_exp2f(x); }
#else
__device__ __forceinline__ float fexp2(float x) { return exp2f(x); }
#endif

// half swap via BUILTIN (hazard-modeled): a'[32:63]=b[0:31], b'[0:31]=a[32:63]
#if __has_builtin(__builtin_amdgcn_permlane32_swap)
__device__ __forceinline__ void half_swap(int& a, int& b) {
  auto r = __builtin_amdgcn_permlane32_swap(a, b, false, false);
  a = (int)r[0]; b = (int)r[1];
}
__device__ __forceinline__ float red_max32(float x) {
  int xi = __builtin_bit_cast(int, x);
  auto r = __builtin_amdgcn_permlane32_swap(xi, xi, false, false);
  return fmaxf(__builtin_bit_cast(float, (int)r[0]), __builtin_bit_cast(float, (int)r[1]));
}
__device__ __forceinline__ float red_add32(float x) {
  int xi = __builtin_bit_cast(int, x);
  auto r = __builtin_amdgcn_permlane32_swap(xi, xi, false, false);
  return __builtin_bit_cast(float, (int)r[0]) + __builtin_bit_cast(float, (int)r[1]);
}
#else
__device__ __forceinline__ void half_swap(int& a, int& b) {
  int as = __shfl_xor(a, 32);
  int bs = __shfl_xor(b, 32);
  int lane = threadIdx.x & 63;
  int na = (lane < 32) ? a : bs;
  int nb = (lane < 32) ? as : b;
  a = na; b = nb;
}
__device__ __forceinline__ float red_max32(float x) { return fmaxf(x, __shfl_xor(x, 32)); }
__device__ __forceinline__ float red_add32(float x) { return x + __shfl_xor(x, 32); }
#endif

// async global->LDS, 16 bytes per lane; LDS dest wave-uniform base (+lane*16 by HW)
__device__ __forceinline__ void gload16(const void* g, void* l) {
  __builtin_amdgcn_global_load_lds(
      reinterpret_cast<const __attribute__((address_space(1))) void*>(reinterpret_cast<uintptr_t>(g)),
      reinterpret_cast<__attribute__((address_space(3))) void*>(reinterpret_cast<uintptr_t>(l)),
      16, 0, 0);
}

// ---------------- converts ----------------
__global__ void k_cvt_bf16(const float* __restrict__ in, u16* __restrict__ out, int n4) {
  int i = blockIdx.x * blockDim.x + threadIdx.x;
  if (i < n4) {
    float4 v = ((const float4*)in)[i];
    ushort4 o;
    o.x = f2bf(v.x); o.y = f2bf(v.y); o.z = f2bf(v.z); o.w = f2bf(v.w);
    ((ushort4*)out)[i] = o;
  }
}

// in: (K x N) f32 row-major  ->  out rows [rowOff .. rowOff+N): (N x K) bf16
__global__ void k_transpose_bf16(const float* __restrict__ in, u16* __restrict__ out,
                                 int K, int N, int rowOff) {
  __shared__ float t[64][65];
  int c0 = blockIdx.x * 64;   // N dim
  int r0 = blockIdx.y * 64;   // K dim
  int tid = threadIdx.x;
  int lr = tid >> 6;          // 0..3
  int lc = tid & 63;
#pragma unroll
  for (int i = 0; i < 16; ++i) {
    int r = lr + i * 4;
    t[r][lc] = in[(size_t)(r0 + r) * N + c0 + lc];
  }
  __syncthreads();
#pragma unroll
  for (int i = 0; i < 16; ++i) {
    int r = lr + i * 4;  // row of transposed tile (= col of in)
    out[(size_t)(rowOff + c0 + r) * K + r0 + lc] = f2bf(t[lc][r]);
  }
}

__global__ void k_bias_concat(const float* __restrict__ bq, const float* __restrict__ bk,
                              const float* __restrict__ bv, float* __restrict__ out) {
  int i = blockIdx.x * 256 + threadIdx.x;
  if (i < NQKV) out[i] = (i < 2048) ? bq[i] : (i < NQK ? bk[i - 2048] : bv[i - NQK]);
}

// ---------------- GEMM: C(MxN) = A(MxK) * Bt(NxK)^T + bias  (R4-proven) ----------
__device__ __forceinline__ void stage_tile(const u16* __restrict__ G, int ldg, int row0, int kt,
                                           u16* lbase, int wid, int lane) {
#pragma unroll
  for (int i = 0; i < 4; ++i) {
    int c   = (wid * 4 + i) * 64 + lane;
    int row = c >> 3, cin = c & 7;
    int cs  = cin ^ (row & 7);  // source pre-swizzle (rule #21)
    const u16* g = G + (size_t)(row0 + row) * ldg + kt * 64 + cs * 8;
    gload16(g, (char*)lbase + (wid * 4 + i) * 1024);
  }
}

template <int OMODE>
__global__ __launch_bounds__(256)
void k_gemm(const u16* __restrict__ A, const u16* __restrict__ Bt,
            const float* __restrict__ bias, void* __restrict__ Cout,
            u16* __restrict__ vt, int M, int N, int K) {
  __shared__ u16 lA[2][128 * 64];
  __shared__ u16 lB[2][128 * 64];
  const int tid = threadIdx.x, lane = tid & 63, wid = tid >> 6;
  const int wm = wid >> 1, wn = wid & 1;
  const int tm = blockIdx.x, tn = blockIdx.y;
  const int nk = K >> 6;

  stage_tile(A, K, tm * 128, 0, lA[0], wid, lane);
  stage_tile(Bt, K, tn * 128, 0, lB[0], wid, lane);
  __syncthreads();

  floatx4 acc[4][4] = {};
  int buf = 0;
  for (int kt = 0; kt < nk; ++kt) {
    if (kt + 1 < nk) {
      stage_tile(A, K, tm * 128, kt + 1, lA[buf ^ 1], wid, lane);
      stage_tile(Bt, K, tn * 128, kt + 1, lB[buf ^ 1], wid, lane);
    }
    const char* pa = (const char*)&lA[buf][0];
    const char* pb = (const char*)&lB[buf][0];
#pragma unroll
    for (int kk = 0; kk < 2; ++kk) {
      bf16x8 af[4], bfr[4];
      int gch = kk * 4 + (lane >> 4);
#pragma unroll
      for (int f = 0; f < 4; ++f) {
        int ra = wm * 64 + f * 16 + (lane & 15);
        af[f]  = *(const bf16x8*)(pa + ra * 128 + ((gch ^ (ra & 7)) << 4));
        int rb = wn * 64 + f * 16 + (lane & 15);
        bfr[f] = *(const bf16x8*)(pb + rb * 128 + ((gch ^ (rb & 7)) << 4));
      }
      __builtin_amdgcn_s_setprio(1);
#pragma unroll
      for (int fm = 0; fm < 4; ++fm)
#pragma unroll
        for (int fn = 0; fn < 4; ++fn)
          acc[fm][fn] = __builtin_amdgcn_mfma_f32_16x16x32_bf16(af[fm], bfr[fn], acc[fm][fn], 0, 0, 0);
      __builtin_amdgcn_s_setprio(0);
    }
    __syncthreads();
    buf ^= 1;
  }

#pragma unroll
  for (int fm = 0; fm < 4; ++fm)
#pragma unroll
    for (int fn = 0; fn < 4; ++fn)
#pragma unroll
      for (int r = 0; r < 4; ++r) {
        int rowg = tm * 128 + wm * 64 + fm * 16 + (lane >> 4) * 4 + r;
        int colg = tn * 128 + wn * 64 + fn * 16 + (lane & 15);
        float v = acc[fm][fn][r] + bias[colg];
        if constexpr (OMODE == 1) {
          ((float*)Cout)[(size_t)rowg * N + colg] = v;
        } else {
          if (colg < NQK) {
            ((u16*)Cout)[(size_t)rowg * N + colg] = f2bf(v);
          } else {  // V: store transposed vt[b][d][s]
            int d = colg - NQK;
            int bg = rowg >> 11, s = rowg & 2047;
            vt[((size_t)bg * HD + d) * S_LEN + s] = f2bf(v);
          }
        }
      }
}

// ---------------- flash attention, SPLIT-K over key range -----------------------
// grid (S/32, 4, B): y&1 = head-group (8 heads/block), y>>1 = key-half kh.
// Each block: 512 thr = 8 waves, 16 K-tiles of 64 keys. LDS 72KB -> 2 blocks/CU.
// Partial output: normalized O (bf16) into pO[kh]; per-(b,h,sq) weight
// m+log2(l) stashed in the unused V-column slack of the qkv buffer.
__device__ __forceinline__ void stage_kv(const u16* __restrict__ qkv, const u16* __restrict__ vt,
                                         int b, int kt, u16* lK, u16* lV, int wid, int lane) {
#pragma unroll
  for (int i = 0; i < 2; ++i) {
    int seg = wid * 2 + i;
    {  // K tile: 64 rows x 256B (16 chunks), slot cin holds logical cin^(r&7)
      int r = seg * 4 + (lane >> 4), cin = lane & 15;
      const u16* g = qkv + (size_t)(b * S_LEN + kt * 64 + r) * NQKV + 2048 + ((cin ^ (r & 7)) * 8);
      gload16(g, (char*)lK + seg * 1024);
    }
    {  // Vt tile: 128 rows x 128B (8 chunks)
      int r = seg * 8 + (lane >> 3), cin = lane & 7;
      const u16* g = vt + ((size_t)b * HD + r) * S_LEN + kt * 64 + ((cin ^ (r & 7)) * 8);
      gload16(g, (char*)lV + seg * 1024);
    }
  }
}

// mask tile -> bf16 LDS, pre-scaled by LOG2E. rows 32 x 64 cols; 8B chunks, 2-way swizzle.
__device__ __forceinline__ void mask_write(u16* lMb, int mq, int mc, floatx4 m) {
  intx2 w;
  w[0] = cvtpk(m[0] * LOG2E, m[1] * LOG2E);
  w[1] = cvtpk(m[2] * LOG2E, m[3] * LOG2E);
  *(intx2*)((char*)lMb + mq * 128 + ((mc ^ (mq & 15)) << 3)) = w;
}

__global__ __launch_bounds__(512)
void k_attn(const u16* __restrict__ qkv, const u16* __restrict__ vt,
            const float* __restrict__ mask, u16* __restrict__ pO0,
            u16* __restrict__ pO1, float* __restrict__ qkvf) {
  __shared__ __align__(16) u16 lK[2][64 * 128];   // 32KB
  __shared__ __align__(16) u16 lV[2][128 * 64];   // 32KB
  __shared__ __align__(16) u16 lMb[2][32 * 64];   // 8KB (bf16 mask * LOG2E)
  const int tid = threadIdx.x, lane = tid & 63, wid = tid >> 6;
  const int qt = blockIdx.x, hg = blockIdx.y & 1, kh = blockIdx.y >> 1, b = blockIdx.z;
  const int h = hg * 8 + wid;
  const int q = lane & 31, h5 = lane >> 5;
  const float c_sl2 = 0.08838834764831845f * LOG2E;  // scale * log2(e)
  const int kt0 = kh * (NT / 2), kt1 = kt0 + (NT / 2);

  // hoist Q (B-frag: col=q, d = cs*16 + h5*8 + idx)
  bf16x8 qf[8];
  const size_t qrow = (size_t)(b * S_LEN + qt * 32 + q);
#pragma unroll
  for (int cs = 0; cs < 8; ++cs)
    qf[cs] = *(const bf16x8*)(qkv + qrow * NQKV + h * HD + cs * 16 + h5 * 8);

  float m_ = -1e30f, l_ = 0.f;   // log2-domain running max / sum
  floatx16 acco[4] = {};         // O^T: col=q (lane-local), row = d

  // mask stage helpers
  const int mq = tid >> 4, mc = tid & 15;
  const float* mrow = mask + (size_t)b * S_LEN * S_LEN + (size_t)(qt * 32 + mq) * S_LEN + mc * 4;

  // prologue: stage kt0
  stage_kv(qkv, vt, b, kt0, lK[0], lV[0], wid, lane);
  floatx4 mreg = *(const floatx4*)(mrow + (size_t)kt0 * 64);
  mask_write(&lMb[0][0], mq, mc, mreg);
  __syncthreads();

  int buf = 0;
  for (int kt = kt0; kt < kt1; ++kt) {
    if (kt + 1 < kt1) {
      stage_kv(qkv, vt, b, kt + 1, lK[buf ^ 1], lV[buf ^ 1], wid, lane);
      mreg = *(const floatx4*)(mrow + (size_t)(kt + 1) * 64);
    }

    // ---- QK^T swapped: accs = K * Q^T = S^T (col = q = lane&31) ----
    floatx16 accs0 = {}, accs1 = {};
    const char* pK = (const char*)&lK[buf][0];
    __builtin_amdgcn_s_setprio(1);
#pragma unroll
    for (int cs = 0; cs < 8; ++cs) {
      int c = cs * 2 + h5;
      bf16x8 kf0 = *(const bf16x8*)(pK + q * 256 + ((c ^ (q & 7)) << 4));
      bf16x8 kf1 = *(const bf16x8*)(pK + (32 + q) * 256 + ((c ^ (q & 7)) << 4));
      accs0 = mfma32(kf0, qf[cs], accs0, 0, 0, 0);
      accs1 = mfma32(kf1, qf[cs], accs1, 0, 0, 0);
    }
    __builtin_amdgcn_s_setprio(0);

    // ---- online softmax, log2 domain, bf16 mask from LDS ----
    float pr[32];
    float pm0 = -1e30f, pm1 = -1e30f, pm2 = -1e30f, pm3 = -1e30f;
    const char* pM = (const char*)&lMb[buf][0];
#pragma unroll
    for (int kb = 0; kb < 2; ++kb)
#pragma unroll
      for (int rg = 0; rg < 4; ++rg) {
        int c = kb * 8 + rg * 2 + h5;
        ushort4 mu = *(const ushort4*)(pM + q * 128 + ((c ^ (q & 15)) << 3));
        float s0 = (kb ? accs1[rg * 4 + 0] : accs0[rg * 4 + 0]) * c_sl2 + bf2f(mu.x);
        float s1 = (kb ? accs1[rg * 4 + 1] : accs0[rg * 4 + 1]) * c_sl2 + bf2f(mu.y);
        float s2 = (kb ? accs1[rg * 4 + 2] : accs0[rg * 4 + 2]) * c_sl2 + bf2f(mu.z);
        float s3 = (kb ? accs1[rg * 4 + 3] : accs0[rg * 4 + 3]) * c_sl2 + bf2f(mu.w);
        pr[kb * 16 + rg * 4 + 0] = s0; pm0 = fmaxf(pm0, s0);
        pr[kb * 16 + rg * 4 + 1] = s1; pm1 = fmaxf(pm1, s1);
        pr[kb * 16 + rg * 4 + 2] = s2; pm2 = fmaxf(pm2, s2);
        pr[kb * 16 + rg * 4 + 3] = s3; pm3 = fmaxf(pm3, s3);
      }
    float rowm = red_max32(fmaxf(fmaxf(pm0, pm1), fmaxf(pm2, pm3)));

    // defer-max (T13): only rescale when max grows by > 8/ln2 (log2 units)
    if (__any(rowm > m_ + 11.5415603f)) {
      float mn = fmaxf(m_, rowm);
      float al = fexp2(m_ - mn);
      m_ = mn;
      l_ *= al;
#pragma unroll
      for (int dt = 0; dt < 4; ++dt) acco[dt] *= al;
    }
    float ps0 = 0.f, ps1 = 0.f, ps2 = 0.f, ps3 = 0.f;
#pragma unroll
    for (int j = 0; j < 32; j += 4) {
      float e0 = fexp2(pr[j + 0] - m_); pr[j + 0] = e0; ps0 += e0;
      float e1 = fexp2(pr[j + 1] - m_); pr[j + 1] = e1; ps1 += e1;
      float e2 = fexp2(pr[j + 2] - m_); pr[j + 2] = e2; ps2 += e2;
      float e3 = fexp2(pr[j + 3] - m_); pr[j + 3] = e3; ps3 += e3;
    }
    l_ += red_add32((ps0 + ps1) + (ps2 + ps3));

    // ---- pack P into PV B-fragments (cvt_pk + permlane32_swap, no LDS/DS) ----
    bf16x8 pf[4];
#pragma unroll
    for (int kb = 0; kb < 2; ++kb)
#pragma unroll
      for (int s = 0; s < 2; ++s) {
        int base = kb * 16 + s * 8;
        int A0 = cvtpk(pr[base + 0], pr[base + 1]);
        int A1 = cvtpk(pr[base + 2], pr[base + 3]);
        int B0 = cvtpk(pr[base + 4], pr[base + 5]);
        int B1 = cvtpk(pr[base + 6], pr[base + 7]);
        half_swap(A0, B0);
        half_swap(A1, B1);
        intx4 w;
        w[0] = A0; w[1] = A1; w[2] = B0; w[3] = B1;
        pf[kb * 2 + s] = __builtin_bit_cast(bf16x8, w);
      }

    // ---- PV swapped: acco += Vt * P^T = O^T (col = q) ----
    const char* pV = (const char*)&lV[buf][0];
    __builtin_amdgcn_s_setprio(1);
#pragma unroll
    for (int dt = 0; dt < 4; ++dt) {
      int rd = dt * 32 + q;
#pragma unroll
      for (int ks = 0; ks < 4; ++ks) {
        int c = ks * 2 + h5;
        bf16x8 vf = *(const bf16x8*)(pV + rd * 128 + ((c ^ (q & 7)) << 4));
        acco[dt] = mfma32(vf, pf[ks], acco[dt], 0, 0, 0);
      }
    }
    __builtin_amdgcn_s_setprio(0);

    if (kt + 1 < kt1)
      mask_write(&lMb[buf ^ 1][0], mq, mc, mreg);
    __syncthreads();
    buf ^= 1;
  }

  // ---- epilogue: partial = O/l (bf16) + weight m+log2(l) into qkv V-slack ----
  float inv = 1.0f / l_;
  u16* obase = (kh ? pO1 : pO0) + qrow * DIMSZ + h * HD;
#pragma unroll
  for (int dt = 0; dt < 4; ++dt)
#pragma unroll
    for (int rg = 0; rg < 4; ++rg) {
      int d0 = dt * 32 + rg * 8 + h5 * 4;
      ushort4 st;
      st.x = f2bf(acco[dt][rg * 4 + 0] * inv);
      st.y = f2bf(acco[dt][rg * 4 + 1] * inv);
      st.z = f2bf(acco[dt][rg * 4 + 2] * inv);
      st.w = f2bf(acco[dt][rg * 4 + 3] * inv);
      *(ushort4*)(obase + d0) = st;
    }
  if (h5 == 0) {
    float mtil = m_ + __log2f(l_);
    int j = kh * 65536 + (b * NH + h) * S_LEN + qt * 32 + q;
    qkvf[(size_t)(j >> 6) * (NQKV / 2) + (NQK / 2) + (j & 63)] = mtil;
  }
}

// ---------------- LSE merge of the two key-halves ----------------
__global__ __launch_bounds__(256)
void k_merge(const u16* __restrict__ p0, u16* __restrict__ p1,
             const float* __restrict__ qkvf) {
  int idx = blockIdx.x * 256 + threadIdx.x;   // [0, 4096*2048/8)
  size_t gi = (size_t)idx * 8;
  int row = (int)(gi >> 11);                  // b*S + sq
  int col = (int)(gi & 2047);
  int h = col >> 7;
  int b = row >> 11, sq = row & 2047;
  int j0 = (b * NH + h) * S_LEN + sq;
  int j1 = 65536 + j0;
  float mt0 = qkvf[(size_t)(j0 >> 6) * (NQKV / 2) + (NQK / 2) + (j0 & 63)];
  float mt1 = qkvf[(size_t)(j1 >> 6) * (NQKV / 2) + (NQK / 2) + (j1 & 63)];
  float M = fmaxf(mt0, mt1);
  float w0 = fexp2(mt0 - M), w1 = fexp2(mt1 - M);
  float inv = 1.0f / (w0 + w1);
  w0 *= inv; w1 *= inv;
  intx4 a = *(const intx4*)(p0 + gi);
  intx4 c = *(const intx4*)(p1 + gi);
  intx4 o;
#pragma unroll
  for (int i = 0; i < 4; ++i) {
    unsigned int wa = (unsigned int)a[i], wc = (unsigned int)c[i];
    float lo = w0 * __builtin_bit_cast(float, wa << 16) +
               w1 * __builtin_bit_cast(float, wc << 16);
    float hi = w0 * __builtin_bit_cast(float, wa & 0xFFFF0000u) +
               w1 * __builtin_bit_cast(float, wc & 0xFFFF0000u);
    o[i] = cvtpk(lo, hi);
  }
  *(intx4*)(p1 + gi) = o;
}

// ---------------- launch ----------------
extern "C" void kernel_launch(void* const* d_in, const int* in_sizes, int n_in,
                              void* d_out, int out_size, void* d_ws, size_t ws_size,
                              hipStream_t stream) {
  const float* hidden = (const float*)d_in[0];
  const float* mask   = (const float*)d_in[1];
  const float* wq = (const float*)d_in[2];
  const float* bq = (const float*)d_in[3];
  const float* wk = (const float*)d_in[4];
  const float* bk = (const float*)d_in[5];
  const float* wv = (const float*)d_in[6];
  const float* bv = (const float*)d_in[7];
  const float* wo = (const float*)d_in[8];
  const float* bo = (const float*)d_in[9];
  float* out = (float*)d_out;

  // workspace layout (total ~71.3 MB)
  char* ws = (char*)d_ws;
  u16*   hb    = (u16*)(ws);                    // hidden bf16 4096x2048; REUSED as attn partial kh=0
  u16*   wqkvT = (u16*)(ws + 16777216);         // [wq^T; wk^T; wv^T]: 2304x2048
  u16*   woT   = (u16*)(ws + 26214400);         // wo^T: 2048x2048
  float* bqkv  = (float*)(ws + 34603008);       // 2304 f32
  u16*   qkv   = (u16*)(ws + 34612224);         // 4096x2304 (V cols = ml slack)
  u16*   vt    = (u16*)(ws + 53486592);         // 2 x 128 x 2048
  u16*   attn  = (u16*)(ws + 54535168);         // 4096x2048; partial kh=1, then merged

  k_cvt_bf16<<<dim3(8192), dim3(256), 0, stream>>>(hidden, hb, 4096 * 2048 / 4);
  k_transpose_bf16<<<dim3(32, 32), dim3(256), 0, stream>>>(wq, wqkvT, 2048, 2048, 0);
  k_transpose_bf16<<<dim3(2, 32),  dim3(256), 0, stream>>>(wk, wqkvT, 2048, 128, 2048);
  k_transpose_bf16<<<dim3(2, 32),  dim3(256), 0, stream>>>(wv, wqkvT, 2048, 128, NQK);
  k_transpose_bf16<<<dim3(32, 32), dim3(256), 0, stream>>>(wo, woT, 2048, 2048, 0);
  k_bias_concat<<<dim3(9), dim3(256), 0, stream>>>(bq, bk, bv, bqkv);

  k_gemm<0><<<dim3(32, 18), dim3(256), 0, stream>>>(hb, wqkvT, bqkv, (void*)qkv, vt, 4096, NQKV, 2048);
  k_attn<<<dim3(64, 4, 2), dim3(512), 0, stream>>>(qkv, vt, mask, hb, attn, (float*)qkv);
  k_merge<<<dim3(4096), dim3(256), 0, stream>>>(hb, attn, (const float*)qkv);
  k_gemm<1><<<dim3(32, 16), dim3(256), 0, stream>>>(attn, woT, bo, (void*)out, (u16*)nullptr, 4096, 2048, 2048);
}

// Round 11
// 213.695 us; speedup vs baseline: 1.0345x; 1.0345x over previous
//
#include <hip/hip_runtime.h>
#include <hip/hip_bf16.h>
#include <stdint.h>

#define S_LEN 2048
#define DIMSZ 2048
#define NH    16
#define HD    128
#define NQK   2176   // Q cols (2048) + K cols (128); V cols start here
#define NQKV  2304
#define NT2   (S_LEN / 128)

typedef short  bf16x8  __attribute__((ext_vector_type(8)));
typedef float  floatx4 __attribute__((ext_vector_type(4)));
typedef float  floatx16 __attribute__((ext_vector_type(16)));
typedef int    intx4   __attribute__((ext_vector_type(4)));
typedef unsigned short u16;

#define mfma32 __builtin_amdgcn_mfma_f32_32x32x16_bf16
#define LOG2E 1.4426950408889634f

// round-to-nearest-even f32 -> bf16 bits
__device__ __forceinline__ u16 f2bf(float x) {
  unsigned int u = __builtin_bit_cast(unsigned int, x);
  u = (u + 0x7FFFu + ((u >> 16) & 1u)) >> 16;
  return (u16)u;
}
__device__ __forceinline__ float bf2f(unsigned int bits) {
  return __builtin_bit_cast(float, bits << 16);
}

// v_cvt_pk_bf16_f32: word = (bf16(hi)<<16) | bf16(lo)   (plain VALU, no hazard)
__device__ __forceinline__ int cvtpk(float lo, float hi) {
  int r;
  asm("v_cvt_pk_bf16_f32 %0, %1, %2" : "=v"(r) : "v"(lo), "v"(hi));
  return r;
}

// 2^x — builtin so the compiler handles the TRANS wait-state hazard
#if __has_builtin(__builtin_amdgcn_exp2f)
__device__ __forceinline__ float fexp2(float x) { return __builtin_amdgcn_exp2f(x); }
#else
__device__ __forceinline__ float fexp2(float x) { return exp2f(x); }
#endif

// half swap via BUILTIN (hazard-modeled): a'[32:63]=b[0:31], b'[0:31]=a[32:63]
#if __has_builtin(__builtin_amdgcn_permlane32_swap)
__device__ __forceinline__ void half_swap(int& a, int& b) {
  auto r = __builtin_amdgcn_permlane32_swap(a, b, false, false);
  a = (int)r[0]; b = (int)r[1];
}
__device__ __forceinline__ float red_max32(float x) {
  int xi = __builtin_bit_cast(int, x);
  auto r = __builtin_amdgcn_permlane32_swap(xi, xi, false, false);
  return fmaxf(__builtin_bit_cast(float, (int)r[0]), __builtin_bit_cast(float, (int)r[1]));
}
__device__ __forceinline__ float red_add32(float x) {
  int xi = __builtin_bit_cast(int, x);
  auto r = __builtin_amdgcn_permlane32_swap(xi, xi, false, false);
  return __builtin_bit_cast(float, (int)r[0]) + __builtin_bit_cast(float, (int)r[1]);
}
#else
__device__ __forceinline__ void half_swap(int& a, int& b) {
  int as = __shfl_xor(a, 32);
  int bs = __shfl_xor(b, 32);
  int lane = threadIdx.x & 63;
  int na = (lane < 32) ? a : bs;
  int nb = (lane < 32) ? as : b;
  a = na; b = nb;
}
__device__ __forceinline__ float red_max32(float x) { return fmaxf(x, __shfl_xor(x, 32)); }
__device__ __forceinline__ float red_add32(float x) { return x + __shfl_xor(x, 32); }
#endif

// async global->LDS, 16 bytes per lane; LDS dest wave-uniform base (+lane*16 by HW)
__device__ __forceinline__ void gload16(const void* g, void* l) {
  __builtin_amdgcn_global_load_lds(
      reinterpret_cast<const __attribute__((address_space(1))) void*>(reinterpret_cast<uintptr_t>(g)),
      reinterpret_cast<__attribute__((address_space(3))) void*>(reinterpret_cast<uintptr_t>(l)),
      16, 0, 0);
}

// ---------------- converts ----------------
__global__ void k_cvt_bf16(const float* __restrict__ in, u16* __restrict__ out, int n4) {
  int i = blockIdx.x * blockDim.x + threadIdx.x;
  if (i < n4) {
    float4 v = ((const float4*)in)[i];
    ushort4 o;
    o.x = f2bf(v.x); o.y = f2bf(v.y); o.z = f2bf(v.z); o.w = f2bf(v.w);
    ((ushort4*)out)[i] = o;
  }
}

// in: (K x N) f32 row-major  ->  out rows [rowOff .. rowOff+N): (N x K) bf16
__global__ void k_transpose_bf16(const float* __restrict__ in, u16* __restrict__ out,
                                 int K, int N, int rowOff) {
  __shared__ float t[64][65];
  int c0 = blockIdx.x * 64;   // N dim
  int r0 = blockIdx.y * 64;   // K dim
  int tid = threadIdx.x;
  int lr = tid >> 6;          // 0..3
  int lc = tid & 63;
#pragma unroll
  for (int i = 0; i < 16; ++i) {
    int r = lr + i * 4;
    t[r][lc] = in[(size_t)(r0 + r) * N + c0 + lc];
  }
  __syncthreads();
#pragma unroll
  for (int i = 0; i < 16; ++i) {
    int r = lr + i * 4;  // row of transposed tile (= col of in)
    out[(size_t)(rowOff + c0 + r) * K + r0 + lc] = f2bf(t[lc][r]);
  }
}

__global__ void k_bias_concat(const float* __restrict__ bq, const float* __restrict__ bk,
                              const float* __restrict__ bv, float* __restrict__ out) {
  int i = blockIdx.x * 256 + threadIdx.x;
  if (i < NQKV) out[i] = (i < 2048) ? bq[i] : (i < NQK ? bk[i - 2048] : bv[i - NQK]);
}

// ---------------- GEMM: C(MxN) = A(MxK) * Bt(NxK)^T + bias  (R4 + T1 XCD swizzle) ----
__device__ __forceinline__ void stage_tile(const u16* __restrict__ G, int ldg, int row0, int kt,
                                           u16* lbase, int wid, int lane) {
#pragma unroll
  for (int i = 0; i < 4; ++i) {
    int c   = (wid * 4 + i) * 64 + lane;
    int row = c >> 3, cin = c & 7;
    int cs  = cin ^ (row & 7);  // source pre-swizzle (rule #21)
    const u16* g = G + (size_t)(row0 + row) * ldg + kt * 64 + cs * 8;
    gload16(g, (char*)lbase + (wid * 4 + i) * 1024);
  }
}

template <int OMODE>
__global__ __launch_bounds__(256)
void k_gemm(const u16* __restrict__ A, const u16* __restrict__ Bt,
            const float* __restrict__ bias, void* __restrict__ Cout,
            u16* __restrict__ vt, int M, int N, int K) {
  __shared__ u16 lA[2][128 * 64];
  __shared__ u16 lB[2][128 * 64];
  const int tid = threadIdx.x, lane = tid & 63, wid = tid >> 6;
  const int wm = wid >> 1, wn = wid & 1;
  // T1: XCD-aware block swizzle (nwg % 8 == 0 for both call sites)
  const int tmN = M >> 7;
  const int nwg = tmN * (N >> 7);
  const int qx = nwg >> 3;
  const int swz = (blockIdx.x & 7) * qx + (blockIdx.x >> 3);
  const int tm = swz % tmN, tn = swz / tmN;
  const int nk = K >> 6;

  stage_tile(A, K, tm * 128, 0, lA[0], wid, lane);
  stage_tile(Bt, K, tn * 128, 0, lB[0], wid, lane);
  __syncthreads();

  floatx4 acc[4][4] = {};
  int buf = 0;
  for (int kt = 0; kt < nk; ++kt) {
    if (kt + 1 < nk) {
      stage_tile(A, K, tm * 128, kt + 1, lA[buf ^ 1], wid, lane);
      stage_tile(Bt, K, tn * 128, kt + 1, lB[buf ^ 1], wid, lane);
    }
    const char* pa = (const char*)&lA[buf][0];
    const char* pb = (const char*)&lB[buf][0];
#pragma unroll
    for (int kk = 0; kk < 2; ++kk) {
      bf16x8 af[4], bfr[4];
      int gch = kk * 4 + (lane >> 4);
#pragma unroll
      for (int f = 0; f < 4; ++f) {
        int ra = wm * 64 + f * 16 + (lane & 15);
        af[f]  = *(const bf16x8*)(pa + ra * 128 + ((gch ^ (ra & 7)) << 4));
        int rb = wn * 64 + f * 16 + (lane & 15);
        bfr[f] = *(const bf16x8*)(pb + rb * 128 + ((gch ^ (rb & 7)) << 4));
      }
      __builtin_amdgcn_s_setprio(1);
#pragma unroll
      for (int fm = 0; fm < 4; ++fm)
#pragma unroll
        for (int fn = 0; fn < 4; ++fn)
          acc[fm][fn] = __builtin_amdgcn_mfma_f32_16x16x32_bf16(af[fm], bfr[fn], acc[fm][fn], 0, 0, 0);
      __builtin_amdgcn_s_setprio(0);
    }
    __syncthreads();
    buf ^= 1;
  }

#pragma unroll
  for (int fm = 0; fm < 4; ++fm)
#pragma unroll
    for (int fn = 0; fn < 4; ++fn)
#pragma unroll
      for (int r = 0; r < 4; ++r) {
        int rowg = tm * 128 + wm * 64 + fm * 16 + (lane >> 4) * 4 + r;
        int colg = tn * 128 + wn * 64 + fn * 16 + (lane & 15);
        float v = acc[fm][fn][r] + bias[colg];
        if constexpr (OMODE == 1) {
          ((float*)Cout)[(size_t)rowg * N + colg] = v;
        } else {
          if (colg < NQK) {
            ((u16*)Cout)[(size_t)rowg * N + colg] = f2bf(v);
          } else {  // V: store transposed vt[b][d][s]
            int d = colg - NQK;
            int bg = rowg >> 11, s = rowg & 2047;
            vt[((size_t)bg * HD + d) * S_LEN + s] = f2bf(v);
          }
        }
      }
}

// ---------------- flash attention (8-wave, swapped-operand, KVBLK=128, lM bf16) ----
// grid (S/32, 2, B); 512 threads = 8 waves; wave w = head hg*8+w, all on same 32 q-rows.
// K tile 128x128 (256B rows), Vt tile 128x128, mask 32x128 bf16 (pre-scaled by LOG2E).
__device__ __forceinline__ void stage_kv128(const u16* __restrict__ qkv, const u16* __restrict__ vt,
                                            int b, int kt, u16* lK, u16* lV, int wid, int lane) {
#pragma unroll
  for (int i = 0; i < 4; ++i) {
    int seg = wid * 4 + i;             // 0..31, 1KB each
    int r = seg * 4 + (lane >> 4);     // row 0..127
    int cin = lane & 15;
    int cs = cin ^ (r & 7);            // source pre-swizzle (rule #21)
    const u16* gk = qkv + (size_t)(b * S_LEN + kt * 128 + r) * NQKV + 2048 + cs * 8;
    gload16(gk, (char*)lK + seg * 1024);
    const u16* gv = vt + ((size_t)b * HD + r) * S_LEN + kt * 128 + cs * 8;
    gload16(gv, (char*)lV + seg * 1024);
  }
}

// mask tile -> bf16 LDS pre-scaled by LOG2E; 32 rows x 256B, 16B chunks, XOR-swizzled
__device__ __forceinline__ void mask_write128(u16* lMb, int mq, int mc, floatx4 m0, floatx4 m1) {
  intx4 w;
  w[0] = cvtpk(m0[0] * LOG2E, m0[1] * LOG2E);
  w[1] = cvtpk(m0[2] * LOG2E, m0[3] * LOG2E);
  w[2] = cvtpk(m1[0] * LOG2E, m1[1] * LOG2E);
  w[3] = cvtpk(m1[2] * LOG2E, m1[3] * LOG2E);
  *(intx4*)((char*)lMb + mq * 256 + ((mc ^ (mq & 7)) << 4)) = w;
}

__global__ __launch_bounds__(512)
void k_attn(const u16* __restrict__ qkv, const u16* __restrict__ vt,
            const float* __restrict__ mask, u16* __restrict__ attn) {
  __shared__ __align__(16) u16 lK[2][128 * 128];   // 64KB
  __shared__ __align__(16) u16 lV[2][128 * 128];   // 64KB
  __shared__ __align__(16) u16 lMb[2][32 * 128];   // 16KB
  const int tid = threadIdx.x, lane = tid & 63, wid = tid >> 6;
  const int qt = blockIdx.x, hg = blockIdx.y, b = blockIdx.z;
  const int h = hg * 8 + wid;
  const int q = lane & 31, h5 = lane >> 5;
  const float c_sl2 = 0.08838834764831845f * LOG2E;  // scale * log2(e)

  // hoist Q (B-frag: col=q, d = cs*16 + h5*8 + idx)
  bf16x8 qf[8];
  const size_t qrow = (size_t)(b * S_LEN + qt * 32 + q);
#pragma unroll
  for (int cs = 0; cs < 8; ++cs)
    qf[cs] = *(const bf16x8*)(qkv + qrow * NQKV + h * HD + cs * 16 + h5 * 8);

  // hoisted LDS byte offsets (loop-invariant)
  const int qb = q * 256;
  int offK[8], offVc[8];
#pragma unroll
  for (int cs = 0; cs < 8; ++cs)
    offK[cs] = qb + (((cs * 2 + h5) ^ (q & 7)) << 4);
#pragma unroll
  for (int hf = 0; hf < 2; ++hf)
#pragma unroll
    for (int ks = 0; ks < 4; ++ks)
      offVc[hf * 4 + ks] = (((hf * 8 + ks * 2 + h5) ^ (q & 7)) << 4);

  float m_ = -1e30f, l_ = 0.f;   // log2-domain running max / sum
  floatx16 acco[4] = {};         // O^T: col=q (lane-local), row = d

  // mask stage helpers
  const int mq = tid >> 4, mc = tid & 15;
  const float* mrow = mask + (size_t)b * S_LEN * S_LEN + (size_t)(qt * 32 + mq) * S_LEN + mc * 8;

  // prologue: stage kt=0
  stage_kv128(qkv, vt, b, 0, lK[0], lV[0], wid, lane);
  {
    floatx4 m0 = *(const floatx4*)(mrow);
    floatx4 m1 = *(const floatx4*)(mrow + 4);
    mask_write128(&lMb[0][0], mq, mc, m0, m1);
  }
  __syncthreads();

  int buf = 0;
  for (int kt = 0; kt < NT2; ++kt) {
    floatx4 mr0, mr1;
    if (kt + 1 < NT2) {
      stage_kv128(qkv, vt, b, kt + 1, lK[buf ^ 1], lV[buf ^ 1], wid, lane);
      mr0 = *(const floatx4*)(mrow + (size_t)(kt + 1) * 128);
      mr1 = *(const floatx4*)(mrow + (size_t)(kt + 1) * 128 + 4);
    }
    const char* pKb = (const char*)&lK[buf][0];
    const char* pVb = (const char*)&lV[buf][0];
    const char* pMb = (const char*)&lMb[buf][0];

#pragma unroll
    for (int hf = 0; hf < 2; ++hf) {
      // ---- QK^T swapped: accs = K * Q^T = S^T (col = q = lane&31) ----
      floatx16 accs0 = {}, accs1 = {};
      const char* pK = pKb + hf * 16384;
      __builtin_amdgcn_s_setprio(1);
#pragma unroll
      for (int cs = 0; cs < 8; ++cs) {
        bf16x8 kf0 = *(const bf16x8*)(pK + offK[cs]);
        bf16x8 kf1 = *(const bf16x8*)(pK + 8192 + offK[cs]);
        accs0 = mfma32(kf0, qf[cs], accs0, 0, 0, 0);
        accs1 = mfma32(kf1, qf[cs], accs1, 0, 0, 0);
      }
      __builtin_amdgcn_s_setprio(0);

      // ---- online softmax, log2 domain, bf16 mask from LDS ----
      float pr[32];
      float pm0 = -1e30f, pm1 = -1e30f, pm2 = -1e30f, pm3 = -1e30f;
#pragma unroll
      for (int kb = 0; kb < 2; ++kb)
#pragma unroll
        for (int rg = 0; rg < 4; ++rg) {
          ushort4 mu = *(const ushort4*)(pMb + qb +
                         (((hf * 8 + kb * 4 + rg) ^ (q & 7)) << 4) + h5 * 8);
          float s0 = (kb ? accs1[rg * 4 + 0] : accs0[rg * 4 + 0]) * c_sl2 + bf2f(mu.x);
          float s1 = (kb ? accs1[rg * 4 + 1] : accs0[rg * 4 + 1]) * c_sl2 + bf2f(mu.y);
          float s2 = (kb ? accs1[rg * 4 + 2] : accs0[rg * 4 + 2]) * c_sl2 + bf2f(mu.z);
          float s3 = (kb ? accs1[rg * 4 + 3] : accs0[rg * 4 + 3]) * c_sl2 + bf2f(mu.w);
          pr[kb * 16 + rg * 4 + 0] = s0; pm0 = fmaxf(pm0, s0);
          pr[kb * 16 + rg * 4 + 1] = s1; pm1 = fmaxf(pm1, s1);
          pr[kb * 16 + rg * 4 + 2] = s2; pm2 = fmaxf(pm2, s2);
          pr[kb * 16 + rg * 4 + 3] = s3; pm3 = fmaxf(pm3, s3);
        }
      float rowm = red_max32(fmaxf(fmaxf(pm0, pm1), fmaxf(pm2, pm3)));

      // defer-max (T13): only rescale when max grows by > 8/ln2 (log2 units)
      if (__any(rowm > m_ + 11.5415603f)) {
        float mn = fmaxf(m_, rowm);
        float al = fexp2(m_ - mn);
        m_ = mn;
        l_ *= al;
#pragma unroll
        for (int dt = 0; dt < 4; ++dt) acco[dt] *= al;
      }
      float ps0 = 0.f, ps1 = 0.f, ps2 = 0.f, ps3 = 0.f;
#pragma unroll
      for (int j = 0; j < 32; j += 4) {
        float e0 = fexp2(pr[j + 0] - m_); pr[j + 0] = e0; ps0 += e0;
        float e1 = fexp2(pr[j + 1] - m_); pr[j + 1] = e1; ps1 += e1;
        float e2 = fexp2(pr[j + 2] - m_); pr[j + 2] = e2; ps2 += e2;
        float e3 = fexp2(pr[j + 3] - m_); pr[j + 3] = e3; ps3 += e3;
      }
      l_ += red_add32((ps0 + ps1) + (ps2 + ps3));

      // ---- pack P into PV B-fragments (cvt_pk + permlane32_swap, no LDS/DS) ----
      bf16x8 pf[4];
#pragma unroll
      for (int kb = 0; kb < 2; ++kb)
#pragma unroll
        for (int s = 0; s < 2; ++s) {
          int base = kb * 16 + s * 8;
          int A0 = cvtpk(pr[base + 0], pr[base + 1]);
          int A1 = cvtpk(pr[base + 2], pr[base + 3]);
          int B0 = cvtpk(pr[base + 4], pr[base + 5]);
          int B1 = cvtpk(pr[base + 6], pr[base + 7]);
          half_swap(A0, B0);
          half_swap(A1, B1);
          intx4 w;
          w[0] = A0; w[1] = A1; w[2] = B0; w[3] = B1;
          pf[kb * 2 + s] = __builtin_bit_cast(bf16x8, w);
        }

      // ---- PV swapped: acco += Vt * P^T = O^T (col = q) ----
      __builtin_amdgcn_s_setprio(1);
#pragma unroll
      for (int dt = 0; dt < 4; ++dt)
#pragma unroll
        for (int ks = 0; ks < 4; ++ks) {
          bf16x8 vf = *(const bf16x8*)(pVb + dt * 8192 + qb + offVc[hf * 4 + ks]);
          acco[dt] = mfma32(vf, pf[ks], acco[dt], 0, 0, 0);
        }
      __builtin_amdgcn_s_setprio(0);
    }

    if (kt + 1 < NT2)
      mask_write128(&lMb[buf ^ 1][0], mq, mc, mr0, mr1);
    __syncthreads();
    buf ^= 1;
  }

  // ---- epilogue: attn[q][h*HD + d] = O/l ----
  float inv = 1.0f / l_;
  u16* obase = attn + qrow * DIMSZ + h * HD;
#pragma unroll
  for (int dt = 0; dt < 4; ++dt)
#pragma unroll
    for (int rg = 0; rg < 4; ++rg) {
      int d0 = dt * 32 + rg * 8 + h5 * 4;
      ushort4 st;
      st.x = f2bf(acco[dt][rg * 4 + 0] * inv);
      st.y = f2bf(acco[dt][rg * 4 + 1] * inv);
      st.z = f2bf(acco[dt][rg * 4 + 2] * inv);
      st.w = f2bf(acco[dt][rg * 4 + 3] * inv);
      *(ushort4*)(obase + d0) = st;
    }
}

// ---------------- launch ----------------
extern "C" void kernel_launch(void* const* d_in, const int* in_sizes, int n_in,
                              void* d_out, int out_size, void* d_ws, size_t ws_size,
                              hipStream_t stream) {
  const float* hidden = (const float*)d_in[0];
  const float* mask   = (const float*)d_in[1];
  const float* wq = (const float*)d_in[2];
  const float* bq = (const float*)d_in[3];
  const float* wk = (const float*)d_in[4];
  const float* bk = (const float*)d_in[5];
  const float* wv = (const float*)d_in[6];
  const float* bv = (const float*)d_in[7];
  const float* wo = (const float*)d_in[8];
  const float* bo = (const float*)d_in[9];
  float* out = (float*)d_out;

  // workspace layout (total ~71.3 MB)
  char* ws = (char*)d_ws;
  u16*   hb    = (u16*)(ws);                    // hidden bf16: 4096x2048
  u16*   wqkvT = (u16*)(ws + 16777216);         // [wq^T; wk^T; wv^T]: 2304x2048
  u16*   woT   = (u16*)(ws + 26214400);         // wo^T: 2048x2048
  float* bqkv  = (float*)(ws + 34603008);       // 2304 f32
  u16*   qkv   = (u16*)(ws + 34612224);         // 4096x2304
  u16*   vt    = (u16*)(ws + 53486592);         // 2 x 128 x 2048
  u16*   attn  = (u16*)(ws + 54535168);         // 4096x2048

  k_cvt_bf16<<<dim3(8192), dim3(256), 0, stream>>>(hidden, hb, 4096 * 2048 / 4);
  k_transpose_bf16<<<dim3(32, 32), dim3(256), 0, stream>>>(wq, wqkvT, 2048, 2048, 0);
  k_transpose_bf16<<<dim3(2, 32),  dim3(256), 0, stream>>>(wk, wqkvT, 2048, 128, 2048);
  k_transpose_bf16<<<dim3(2, 32),  dim3(256), 0, stream>>>(wv, wqkvT, 2048, 128, NQK);
  k_transpose_bf16<<<dim3(32, 32), dim3(256), 0, stream>>>(wo, woT, 2048, 2048, 0);
  k_bias_concat<<<dim3(9), dim3(256), 0, stream>>>(bq, bk, bv, bqkv);

  k_gemm<0><<<dim3(576), dim3(256), 0, stream>>>(hb, wqkvT, bqkv, (void*)qkv, vt, 4096, NQKV, 2048);
  k_attn<<<dim3(64, 2, 2), dim3(512), 0, stream>>>(qkv, vt, mask, attn);
  k_gemm<1><<<dim3(512), dim3(256), 0, stream>>>(attn, woT, bo, (void*)out, (u16*)nullptr, 4096, 2048, 2048);
}

// Round 12
// 199.683 us; speedup vs baseline: 1.1071x; 1.0702x over previous
//
#include <hip/hip_runtime.h>
#include <hip/hip_bf16.h>
#include <stdint.h>

#define S_LEN 2048
#define DIMSZ 2048
#define NH    16
#define HD    128
#define NQK   2176   // Q cols (2048) + K cols (128); V cols start here
#define NQKV  2304
#define NT2   (S_LEN / 128)

typedef short  bf16x8  __attribute__((ext_vector_type(8)));
typedef float  floatx4 __attribute__((ext_vector_type(4)));
typedef float  floatx16 __attribute__((ext_vector_type(16)));
typedef int    intx4   __attribute__((ext_vector_type(4)));
typedef unsigned short u16;

#define mfma32 __builtin_amdgcn_mfma_f32_32x32x16_bf16
#define LOG2E 1.4426950408889634f

// round-to-nearest-even f32 -> bf16 bits
__device__ __forceinline__ u16 f2bf(float x) {
  unsigned int u = __builtin_bit_cast(unsigned int, x);
  u = (u + 0x7FFFu + ((u >> 16) & 1u)) >> 16;
  return (u16)u;
}
__device__ __forceinline__ float bf2f(unsigned int bits) {
  return __builtin_bit_cast(float, bits << 16);
}

// v_cvt_pk_bf16_f32: word = (bf16(hi)<<16) | bf16(lo)   (plain VALU, no hazard)
__device__ __forceinline__ int cvtpk(float lo, float hi) {
  int r;
  asm("v_cvt_pk_bf16_f32 %0, %1, %2" : "=v"(r) : "v"(lo), "v"(hi));
  return r;
}

// 2^x — builtin so the compiler handles the TRANS wait-state hazard
#if __has_builtin(__builtin_amdgcn_exp2f)
__device__ __forceinline__ float fexp2(float x) { return __builtin_amdgcn_exp2f(x); }
#else
__device__ __forceinline__ float fexp2(float x) { return exp2f(x); }
#endif

// half swap via BUILTIN (hazard-modeled): a'[32:63]=b[0:31], b'[0:31]=a[32:63]
#if __has_builtin(__builtin_amdgcn_permlane32_swap)
__device__ __forceinline__ void half_swap(int& a, int& b) {
  auto r = __builtin_amdgcn_permlane32_swap(a, b, false, false);
  a = (int)r[0]; b = (int)r[1];
}
__device__ __forceinline__ float red_max32(float x) {
  int xi = __builtin_bit_cast(int, x);
  auto r = __builtin_amdgcn_permlane32_swap(xi, xi, false, false);
  return fmaxf(__builtin_bit_cast(float, (int)r[0]), __builtin_bit_cast(float, (int)r[1]));
}
__device__ __forceinline__ float red_add32(float x) {
  int xi = __builtin_bit_cast(int, x);
  auto r = __builtin_amdgcn_permlane32_swap(xi, xi, false, false);
  return __builtin_bit_cast(float, (int)r[0]) + __builtin_bit_cast(float, (int)r[1]);
}
#else
__device__ __forceinline__ void half_swap(int& a, int& b) {
  int as = __shfl_xor(a, 32);
  int bs = __shfl_xor(b, 32);
  int lane = threadIdx.x & 63;
  int na = (lane < 32) ? a : bs;
  int nb = (lane < 32) ? as : b;
  a = na; b = nb;
}
__device__ __forceinline__ float red_max32(float x) { return fmaxf(x, __shfl_xor(x, 32)); }
__device__ __forceinline__ float red_add32(float x) { return x + __shfl_xor(x, 32); }
#endif

// async global->LDS, 16 bytes per lane; LDS dest wave-uniform base (+lane*16 by HW)
__device__ __forceinline__ void gload16(const void* g, void* l) {
  __builtin_amdgcn_global_load_lds(
      reinterpret_cast<const __attribute__((address_space(1))) void*>(reinterpret_cast<uintptr_t>(g)),
      reinterpret_cast<__attribute__((address_space(3))) void*>(reinterpret_cast<uintptr_t>(l)),
      16, 0, 0);
}

// ---------------- converts ----------------
__global__ void k_cvt_bf16(const float* __restrict__ in, u16* __restrict__ out, int n4) {
  int i = blockIdx.x * blockDim.x + threadIdx.x;
  if (i < n4) {
    float4 v = ((const float4*)in)[i];
    ushort4 o;
    o.x = f2bf(v.x); o.y = f2bf(v.y); o.z = f2bf(v.z); o.w = f2bf(v.w);
    ((ushort4*)out)[i] = o;
  }
}

// merged transpose of wq|wk|wv (each K x Nsub, f32) into wqkvT (2304 x 2048) bf16
__global__ void k_transpose_qkv(const float* __restrict__ wq, const float* __restrict__ wk,
                                const float* __restrict__ wv, u16* __restrict__ out, int K) {
  __shared__ float t[64][65];
  int orow0 = blockIdx.x * 64;   // output-row base = source-col base in concat space
  int r0 = blockIdx.y * 64;      // K tile
  const float* src;
  int N, scol0;
  if (orow0 < 2048)      { src = wq; N = 2048; scol0 = orow0; }
  else if (orow0 < NQK)  { src = wk; N = 128;  scol0 = orow0 - 2048; }
  else                   { src = wv; N = 128;  scol0 = orow0 - NQK; }
  int tid = threadIdx.x;
  int lr = tid >> 6;          // 0..3
  int lc = tid & 63;
#pragma unroll
  for (int i = 0; i < 16; ++i) {
    int r = lr + i * 4;
    t[r][lc] = src[(size_t)(r0 + r) * N + scol0 + lc];
  }
  __syncthreads();
#pragma unroll
  for (int i = 0; i < 16; ++i) {
    int r = lr + i * 4;
    out[(size_t)(orow0 + r) * K + r0 + lc] = f2bf(t[lc][r]);
  }
}

// in: (K x N) f32 row-major  ->  out: (N x K) bf16
__global__ void k_transpose_bf16(const float* __restrict__ in, u16* __restrict__ out,
                                 int K, int N) {
  __shared__ float t[64][65];
  int c0 = blockIdx.x * 64;
  int r0 = blockIdx.y * 64;
  int tid = threadIdx.x;
  int lr = tid >> 6;
  int lc = tid & 63;
#pragma unroll
  for (int i = 0; i < 16; ++i) {
    int r = lr + i * 4;
    t[r][lc] = in[(size_t)(r0 + r) * N + c0 + lc];
  }
  __syncthreads();
#pragma unroll
  for (int i = 0; i < 16; ++i) {
    int r = lr + i * 4;
    out[(size_t)(c0 + r) * K + r0 + lc] = f2bf(t[lc][r]);
  }
}

__global__ void k_bias_concat(const float* __restrict__ bq, const float* __restrict__ bk,
                              const float* __restrict__ bv, float* __restrict__ out) {
  int i = blockIdx.x * 256 + threadIdx.x;
  if (i < NQKV) out[i] = (i < 2048) ? bq[i] : (i < NQK ? bk[i - 2048] : bv[i - NQK]);
}

// ---------------- GEMM: C(MxN) = A(MxK) * Bt(NxK)^T + bias  (R8-proven) ----------
__device__ __forceinline__ void stage_tile(const u16* __restrict__ G, int ldg, int row0, int kt,
                                           u16* lbase, int wid, int lane) {
#pragma unroll
  for (int i = 0; i < 4; ++i) {
    int c   = (wid * 4 + i) * 64 + lane;
    int row = c >> 3, cin = c & 7;
    int cs  = cin ^ (row & 7);  // source pre-swizzle (rule #21)
    const u16* g = G + (size_t)(row0 + row) * ldg + kt * 64 + cs * 8;
    gload16(g, (char*)lbase + (wid * 4 + i) * 1024);
  }
}

template <int OMODE>
__global__ __launch_bounds__(256)
void k_gemm(const u16* __restrict__ A, const u16* __restrict__ Bt,
            const float* __restrict__ bias, void* __restrict__ Cout,
            u16* __restrict__ vt, int M, int N, int K) {
  __shared__ u16 lA[2][128 * 64];
  __shared__ u16 lB[2][128 * 64];
  const int tid = threadIdx.x, lane = tid & 63, wid = tid >> 6;
  const int wm = wid >> 1, wn = wid & 1;
  const int tm = blockIdx.x, tn = blockIdx.y;
  const int nk = K >> 6;

  stage_tile(A, K, tm * 128, 0, lA[0], wid, lane);
  stage_tile(Bt, K, tn * 128, 0, lB[0], wid, lane);
  __syncthreads();

  floatx4 acc[4][4] = {};
  int buf = 0;
  for (int kt = 0; kt < nk; ++kt) {
    if (kt + 1 < nk) {
      stage_tile(A, K, tm * 128, kt + 1, lA[buf ^ 1], wid, lane);
      stage_tile(Bt, K, tn * 128, kt + 1, lB[buf ^ 1], wid, lane);
    }
    const char* pa = (const char*)&lA[buf][0];
    const char* pb = (const char*)&lB[buf][0];
#pragma unroll
    for (int kk = 0; kk < 2; ++kk) {
      bf16x8 af[4], bfr[4];
      int gch = kk * 4 + (lane >> 4);
#pragma unroll
      for (int f = 0; f < 4; ++f) {
        int ra = wm * 64 + f * 16 + (lane & 15);
        af[f]  = *(const bf16x8*)(pa + ra * 128 + ((gch ^ (ra & 7)) << 4));
        int rb = wn * 64 + f * 16 + (lane & 15);
        bfr[f] = *(const bf16x8*)(pb + rb * 128 + ((gch ^ (rb & 7)) << 4));
      }
      __builtin_amdgcn_s_setprio(1);
#pragma unroll
      for (int fm = 0; fm < 4; ++fm)
#pragma unroll
        for (int fn = 0; fn < 4; ++fn)
          acc[fm][fn] = __builtin_amdgcn_mfma_f32_16x16x32_bf16(af[fm], bfr[fn], acc[fm][fn], 0, 0, 0);
      __builtin_amdgcn_s_setprio(0);
    }
    __syncthreads();
    buf ^= 1;
  }

#pragma unroll
  for (int fm = 0; fm < 4; ++fm)
#pragma unroll
    for (int fn = 0; fn < 4; ++fn)
#pragma unroll
      for (int r = 0; r < 4; ++r) {
        int rowg = tm * 128 + wm * 64 + fm * 16 + (lane >> 4) * 4 + r;
        int colg = tn * 128 + wn * 64 + fn * 16 + (lane & 15);
        float v = acc[fm][fn][r] + bias[colg];
        if constexpr (OMODE == 1) {
          ((float*)Cout)[(size_t)rowg * N + colg] = v;
        } else {
          if (colg < NQK) {
            ((u16*)Cout)[(size_t)rowg * N + colg] = f2bf(v);
          } else {  // V: store transposed vt[b][d][s]
            int d = colg - NQK;
            int bg = rowg >> 11, s = rowg & 2047;
            vt[((size_t)bg * HD + d) * S_LEN + s] = f2bf(v);
          }
        }
      }
}

// ---------------- flash attention (8-wave, swapped-operand, KVBLK=128, 16-deep swizzle) ----
// grid (S/32, 2, B); 512 threads = 8 waves; wave w = head hg*8+w, all on same 32 q-rows.
// K tile 128x128 (256B rows), Vt tile 128x128, mask 32x128 bf16 (pre-scaled by LOG2E).
// Swizzle: chunk ^ (row & 15) on all three tiles -> 2-way max bank aliasing (free, m136).
__device__ __forceinline__ void stage_kv128(const u16* __restrict__ qkv, const u16* __restrict__ vt,
                                            int b, int kt, u16* lK, u16* lV, int wid, int lane) {
#pragma unroll
  for (int i = 0; i < 4; ++i) {
    int seg = wid * 4 + i;             // 0..31, 1KB each
    int r = seg * 4 + (lane >> 4);     // row 0..127
    int cin = lane & 15;
    int cs = cin ^ (r & 15);           // source pre-swizzle (rule #21)
    const u16* gk = qkv + (size_t)(b * S_LEN + kt * 128 + r) * NQKV + 2048 + cs * 8;
    gload16(gk, (char*)lK + seg * 1024);
    const u16* gv = vt + ((size_t)b * HD + r) * S_LEN + kt * 128 + cs * 8;
    gload16(gv, (char*)lV + seg * 1024);
  }
}

// mask tile -> bf16 LDS pre-scaled by LOG2E; 32 rows x 256B, 16B chunks, 16-deep XOR
__device__ __forceinline__ void mask_write128(u16* lMb, int mq, int mc, floatx4 m0, floatx4 m1) {
  intx4 w;
  w[0] = cvtpk(m0[0] * LOG2E, m0[1] * LOG2E);
  w[1] = cvtpk(m0[2] * LOG2E, m0[3] * LOG2E);
  w[2] = cvtpk(m1[0] * LOG2E, m1[1] * LOG2E);
  w[3] = cvtpk(m1[2] * LOG2E, m1[3] * LOG2E);
  *(intx4*)((char*)lMb + mq * 256 + ((mc ^ (mq & 15)) << 4)) = w;
}

__global__ __launch_bounds__(512)
void k_attn(const u16* __restrict__ qkv, const u16* __restrict__ vt,
            const float* __restrict__ mask, u16* __restrict__ attn) {
  __shared__ __align__(16) u16 lK[2][128 * 128];   // 64KB
  __shared__ __align__(16) u16 lV[2][128 * 128];   // 64KB
  __shared__ __align__(16) u16 lMb[2][32 * 128];   // 16KB
  const int tid = threadIdx.x, lane = tid & 63, wid = tid >> 6;
  const int qt = blockIdx.x, hg = blockIdx.y, b = blockIdx.z;
  const int h = hg * 8 + wid;
  const int q = lane & 31, h5 = lane >> 5;
  const float c_sl2 = 0.08838834764831845f * LOG2E;  // scale * log2(e)

  // hoist Q (B-frag: col=q, d = cs*16 + h5*8 + idx)
  bf16x8 qf[8];
  const size_t qrow = (size_t)(b * S_LEN + qt * 32 + q);
#pragma unroll
  for (int cs = 0; cs < 8; ++cs)
    qf[cs] = *(const bf16x8*)(qkv + qrow * NQKV + h * HD + cs * 16 + h5 * 8);

  // hoisted LDS byte offsets (loop-invariant); row&15 == q&15 for all rows used
  const int qb = q * 256;
  int offK[8], offVc[8], offM[16];
#pragma unroll
  for (int cs = 0; cs < 8; ++cs)
    offK[cs] = qb + (((cs * 2 + h5) ^ (q & 15)) << 4);
#pragma unroll
  for (int hf = 0; hf < 2; ++hf)
#pragma unroll
    for (int ks = 0; ks < 4; ++ks)
      offVc[hf * 4 + ks] = (((hf * 8 + ks * 2 + h5) ^ (q & 15)) << 4);
#pragma unroll
  for (int c = 0; c < 16; ++c)
    offM[c] = qb + ((c ^ (q & 15)) << 4) + h5 * 8;

  float m_ = -1e30f, l_ = 0.f;   // log2-domain running max / sum
  floatx16 acco[4] = {};         // O^T: col=q (lane-local), row = d

  // mask stage helpers
  const int mq = tid >> 4, mc = tid & 15;
  const float* mrow = mask + (size_t)b * S_LEN * S_LEN + (size_t)(qt * 32 + mq) * S_LEN + mc * 8;

  // prologue: stage kt=0
  stage_kv128(qkv, vt, b, 0, lK[0], lV[0], wid, lane);
  {
    floatx4 m0 = *(const floatx4*)(mrow);
    floatx4 m1 = *(const floatx4*)(mrow + 4);
    mask_write128(&lMb[0][0], mq, mc, m0, m1);
  }
  __syncthreads();

  int buf = 0;
  for (int kt = 0; kt < NT2; ++kt) {
    floatx4 mr0, mr1;
    if (kt + 1 < NT2) {
      stage_kv128(qkv, vt, b, kt + 1, lK[buf ^ 1], lV[buf ^ 1], wid, lane);
      mr0 = *(const floatx4*)(mrow + (size_t)(kt + 1) * 128);
      mr1 = *(const floatx4*)(mrow + (size_t)(kt + 1) * 128 + 4);
    }
    const char* pKb = (const char*)&lK[buf][0];
    const char* pVb = (const char*)&lV[buf][0];
    const char* pMb = (const char*)&lMb[buf][0];

#pragma unroll
    for (int hf = 0; hf < 2; ++hf) {
      // ---- QK^T swapped: accs = K * Q^T = S^T (col = q = lane&31) ----
      floatx16 accs0 = {}, accs1 = {};
      const char* pK = pKb + hf * 16384;
      __builtin_amdgcn_s_setprio(1);
#pragma unroll
      for (int cs = 0; cs < 8; ++cs) {
        bf16x8 kf0 = *(const bf16x8*)(pK + offK[cs]);
        bf16x8 kf1 = *(const bf16x8*)(pK + 8192 + offK[cs]);
        accs0 = mfma32(kf0, qf[cs], accs0, 0, 0, 0);
        accs1 = mfma32(kf1, qf[cs], accs1, 0, 0, 0);
      }
      __builtin_amdgcn_s_setprio(0);

      // ---- online softmax, log2 domain, bf16 mask from LDS ----
      float pr[32];
      float pm0 = -1e30f, pm1 = -1e30f, pm2 = -1e30f, pm3 = -1e30f;
#pragma unroll
      for (int kb = 0; kb < 2; ++kb)
#pragma unroll
        for (int rg = 0; rg < 4; ++rg) {
          ushort4 mu = *(const ushort4*)(pMb + offM[hf * 8 + kb * 4 + rg]);
          float s0 = (kb ? accs1[rg * 4 + 0] : accs0[rg * 4 + 0]) * c_sl2 + bf2f(mu.x);
          float s1 = (kb ? accs1[rg * 4 + 1] : accs0[rg * 4 + 1]) * c_sl2 + bf2f(mu.y);
          float s2 = (kb ? accs1[rg * 4 + 2] : accs0[rg * 4 + 2]) * c_sl2 + bf2f(mu.z);
          float s3 = (kb ? accs1[rg * 4 + 3] : accs0[rg * 4 + 3]) * c_sl2 + bf2f(mu.w);
          pr[kb * 16 + rg * 4 + 0] = s0; pm0 = fmaxf(pm0, s0);
          pr[kb * 16 + rg * 4 + 1] = s1; pm1 = fmaxf(pm1, s1);
          pr[kb * 16 + rg * 4 + 2] = s2; pm2 = fmaxf(pm2, s2);
          pr[kb * 16 + rg * 4 + 3] = s3; pm3 = fmaxf(pm3, s3);
        }
      float rowm = red_max32(fmaxf(fmaxf(pm0, pm1), fmaxf(pm2, pm3)));

      // defer-max (T13): only rescale when max grows by > 8/ln2 (log2 units)
      if (__any(rowm > m_ + 11.5415603f)) {
        float mn = fmaxf(m_, rowm);
        float al = fexp2(m_ - mn);
        m_ = mn;
        l_ *= al;
#pragma unroll
        for (int dt = 0; dt < 4; ++dt) acco[dt] *= al;
      }
      float ps0 = 0.f, ps1 = 0.f, ps2 = 0.f, ps3 = 0.f;
#pragma unroll
      for (int j = 0; j < 32; j += 4) {
        float e0 = fexp2(pr[j + 0] - m_); pr[j + 0] = e0; ps0 += e0;
        float e1 = fexp2(pr[j + 1] - m_); pr[j + 1] = e1; ps1 += e1;
        float e2 = fexp2(pr[j + 2] - m_); pr[j + 2] = e2; ps2 += e2;
        float e3 = fexp2(pr[j + 3] - m_); pr[j + 3] = e3; ps3 += e3;
      }
      l_ += red_add32((ps0 + ps1) + (ps2 + ps3));

      // ---- pack P into PV B-fragments (cvt_pk + permlane32_swap, no LDS/DS) ----
      bf16x8 pf[4];
#pragma unroll
      for (int kb = 0; kb < 2; ++kb)
#pragma unroll
        for (int s = 0; s < 2; ++s) {
          int base = kb * 16 + s * 8;
          int A0 = cvtpk(pr[base + 0], pr[base + 1]);
          int A1 = cvtpk(pr[base + 2], pr[base + 3]);
          int B0 = cvtpk(pr[base + 4], pr[base + 5]);
          int B1 = cvtpk(pr[base + 6], pr[base + 7]);
          half_swap(A0, B0);
          half_swap(A1, B1);
          intx4 w;
          w[0] = A0; w[1] = A1; w[2] = B0; w[3] = B1;
          pf[kb * 2 + s] = __builtin_bit_cast(bf16x8, w);
        }

      // ---- PV swapped: acco += Vt * P^T = O^T (col = q) ----
      __builtin_amdgcn_s_setprio(1);
#pragma unroll
      for (int dt = 0; dt < 4; ++dt)
#pragma unroll
        for (int ks = 0; ks < 4; ++ks) {
          bf16x8 vf = *(const bf16x8*)(pVb + dt * 8192 + qb + offVc[hf * 4 + ks]);
          acco[dt] = mfma32(vf, pf[ks], acco[dt], 0, 0, 0);
        }
      __builtin_amdgcn_s_setprio(0);
    }

    if (kt + 1 < NT2)
      mask_write128(&lMb[buf ^ 1][0], mq, mc, mr0, mr1);
    __syncthreads();
    buf ^= 1;
  }

  // ---- epilogue: attn[q][h*HD + d] = O/l ----
  float inv = 1.0f / l_;
  u16* obase = attn + qrow * DIMSZ + h * HD;
#pragma unroll
  for (int dt = 0; dt < 4; ++dt)
#pragma unroll
    for (int rg = 0; rg < 4; ++rg) {
      int d0 = dt * 32 + rg * 8 + h5 * 4;
      ushort4 st;
      st.x = f2bf(acco[dt][rg * 4 + 0] * inv);
      st.y = f2bf(acco[dt][rg * 4 + 1] * inv);
      st.z = f2bf(acco[dt][rg * 4 + 2] * inv);
      st.w = f2bf(acco[dt][rg * 4 + 3] * inv);
      *(ushort4*)(obase + d0) = st;
    }
}

// ---------------- launch ----------------
extern "C" void kernel_launch(void* const* d_in, const int* in_sizes, int n_in,
                              void* d_out, int out_size, void* d_ws, size_t ws_size,
                              hipStream_t stream) {
  const float* hidden = (const float*)d_in[0];
  const float* mask   = (const float*)d_in[1];
  const float* wq = (const float*)d_in[2];
  const float* bq = (const float*)d_in[3];
  const float* wk = (const float*)d_in[4];
  const float* bk = (const float*)d_in[5];
  const float* wv = (const float*)d_in[6];
  const float* bv = (const float*)d_in[7];
  const float* wo = (const float*)d_in[8];
  const float* bo = (const float*)d_in[9];
  float* out = (float*)d_out;

  // workspace layout (total ~71.3 MB)
  char* ws = (char*)d_ws;
  u16*   hb    = (u16*)(ws);                    // hidden bf16: 4096x2048
  u16*   wqkvT = (u16*)(ws + 16777216);         // [wq^T; wk^T; wv^T]: 2304x2048
  u16*   woT   = (u16*)(ws + 26214400);         // wo^T: 2048x2048
  float* bqkv  = (float*)(ws + 34603008);       // 2304 f32
  u16*   qkv   = (u16*)(ws + 34612224);         // 4096x2304
  u16*   vt    = (u16*)(ws + 53486592);         // 2 x 128 x 2048
  u16*   attn  = (u16*)(ws + 54535168);         // 4096x2048

  k_cvt_bf16<<<dim3(8192), dim3(256), 0, stream>>>(hidden, hb, 4096 * 2048 / 4);
  k_transpose_qkv<<<dim3(36, 32), dim3(256), 0, stream>>>(wq, wk, wv, wqkvT, 2048);
  k_transpose_bf16<<<dim3(32, 32), dim3(256), 0, stream>>>(wo, woT, 2048, 2048);
  k_bias_concat<<<dim3(9), dim3(256), 0, stream>>>(bq, bk, bv, bqkv);

  k_gemm<0><<<dim3(32, 18), dim3(256), 0, stream>>>(hb, wqkvT, bqkv, (void*)qkv, vt, 4096, NQKV, 2048);
  k_attn<<<dim3(64, 2, 2), dim3(512), 0, stream>>>(qkv, vt, mask, attn);
  k_gemm<1><<<dim3(32, 16), dim3(256), 0, stream>>>(attn, woT, bo, (void*)out, (u16*)nullptr, 4096, 2048, 2048);
}

// Round 13
// 199.652 us; speedup vs baseline: 1.1073x; 1.0002x over previous
//
#include <hip/hip_runtime.h>
#include <hip/hip_bf16.h>
#include <stdint.h>

#define S_LEN 2048
#define DIMSZ 2048
#define NH    16
#define HD    128
#define NQK   2176   // Q cols (2048) + K cols (128); V cols start here
#define NQKV  2304
#define NT2   (S_LEN / 128)

typedef short  bf16x8  __attribute__((ext_vector_type(8)));
typedef float  floatx4 __attribute__((ext_vector_type(4)));
typedef float  floatx16 __attribute__((ext_vector_type(16)));
typedef int    intx4   __attribute__((ext_vector_type(4)));
typedef unsigned short u16;

#define mfma32 __builtin_amdgcn_mfma_f32_32x32x16_bf16
#define LOG2E 1.4426950408889634f
#define C_SL2 (0.08838834764831845f * LOG2E)   // 1/sqrt(128) * log2(e)

// round-to-nearest-even f32 -> bf16 bits
__device__ __forceinline__ u16 f2bf(float x) {
  unsigned int u = __builtin_bit_cast(unsigned int, x);
  u = (u + 0x7FFFu + ((u >> 16) & 1u)) >> 16;
  return (u16)u;
}
__device__ __forceinline__ float bf2f(unsigned int bits) {
  return __builtin_bit_cast(float, bits << 16);
}

// v_cvt_pk_bf16_f32: word = (bf16(hi)<<16) | bf16(lo)   (plain VALU, no hazard)
__device__ __forceinline__ int cvtpk(float lo, float hi) {
  int r;
  asm("v_cvt_pk_bf16_f32 %0, %1, %2" : "=v"(r) : "v"(lo), "v"(hi));
  return r;
}

// 2^x — builtin so the compiler handles the TRANS wait-state hazard
#if __has_builtin(__builtin_amdgcn_exp2f)
__device__ __forceinline__ float fexp2(float x) { return __builtin_amdgcn_exp2f(x); }
#else
__device__ __forceinline__ float fexp2(float x) { return exp2f(x); }
#endif

// half swap via BUILTIN (hazard-modeled): a'[32:63]=b[0:31], b'[0:31]=a[32:63]
#if __has_builtin(__builtin_amdgcn_permlane32_swap)
__device__ __forceinline__ void half_swap(int& a, int& b) {
  auto r = __builtin_amdgcn_permlane32_swap(a, b, false, false);
  a = (int)r[0]; b = (int)r[1];
}
__device__ __forceinline__ float red_max32(float x) {
  int xi = __builtin_bit_cast(int, x);
  auto r = __builtin_amdgcn_permlane32_swap(xi, xi, false, false);
  return fmaxf(__builtin_bit_cast(float, (int)r[0]), __builtin_bit_cast(float, (int)r[1]));
}
__device__ __forceinline__ float red_add32(float x) {
  int xi = __builtin_bit_cast(int, x);
  auto r = __builtin_amdgcn_permlane32_swap(xi, xi, false, false);
  return __builtin_bit_cast(float, (int)r[0]) + __builtin_bit_cast(float, (int)r[1]);
}
#else
__device__ __forceinline__ void half_swap(int& a, int& b) {
  int as = __shfl_xor(a, 32);
  int bs = __shfl_xor(b, 32);
  int lane = threadIdx.x & 63;
  int na = (lane < 32) ? a : bs;
  int nb = (lane < 32) ? as : b;
  a = na; b = nb;
}
__device__ __forceinline__ float red_max32(float x) { return fmaxf(x, __shfl_xor(x, 32)); }
__device__ __forceinline__ float red_add32(float x) { return x + __shfl_xor(x, 32); }
#endif

// async global->LDS, 16 bytes per lane; LDS dest wave-uniform base (+lane*16 by HW)
__device__ __forceinline__ void gload16(const void* g, void* l) {
  __builtin_amdgcn_global_load_lds(
      reinterpret_cast<const __attribute__((address_space(1))) void*>(reinterpret_cast<uintptr_t>(g)),
      reinterpret_cast<__attribute__((address_space(3))) void*>(reinterpret_cast<uintptr_t>(l)),
      16, 0, 0);
}

// ---------------- converts ----------------
__global__ void k_cvt_bf16(const float* __restrict__ in, u16* __restrict__ out, int n4) {
  int i = blockIdx.x * blockDim.x + threadIdx.x;
  if (i < n4) {
    float4 v = ((const float4*)in)[i];
    ushort4 o;
    o.x = f2bf(v.x); o.y = f2bf(v.y); o.z = f2bf(v.z); o.w = f2bf(v.w);
    ((ushort4*)out)[i] = o;
  }
}

// merged transpose of wq|wk|wv (each K x Nsub, f32) into wqkvT (2304 x 2048) bf16
__global__ void k_transpose_qkv(const float* __restrict__ wq, const float* __restrict__ wk,
                                const float* __restrict__ wv, u16* __restrict__ out, int K) {
  __shared__ float t[64][65];
  int orow0 = blockIdx.x * 64;   // output-row base = source-col base in concat space
  int r0 = blockIdx.y * 64;      // K tile
  const float* src;
  int N, scol0;
  if (orow0 < 2048)      { src = wq; N = 2048; scol0 = orow0; }
  else if (orow0 < NQK)  { src = wk; N = 128;  scol0 = orow0 - 2048; }
  else                   { src = wv; N = 128;  scol0 = orow0 - NQK; }
  int tid = threadIdx.x;
  int lr = tid >> 6;          // 0..3
  int lc = tid & 63;
#pragma unroll
  for (int i = 0; i < 16; ++i) {
    int r = lr + i * 4;
    t[r][lc] = src[(size_t)(r0 + r) * N + scol0 + lc];
  }
  __syncthreads();
#pragma unroll
  for (int i = 0; i < 16; ++i) {
    int r = lr + i * 4;
    out[(size_t)(orow0 + r) * K + r0 + lc] = f2bf(t[lc][r]);
  }
}

// in: (K x N) f32 row-major  ->  out: (N x K) bf16
__global__ void k_transpose_bf16(const float* __restrict__ in, u16* __restrict__ out,
                                 int K, int N) {
  __shared__ float t[64][65];
  int c0 = blockIdx.x * 64;
  int r0 = blockIdx.y * 64;
  int tid = threadIdx.x;
  int lr = tid >> 6;
  int lc = tid & 63;
#pragma unroll
  for (int i = 0; i < 16; ++i) {
    int r = lr + i * 4;
    t[r][lc] = in[(size_t)(r0 + r) * N + c0 + lc];
  }
  __syncthreads();
#pragma unroll
  for (int i = 0; i < 16; ++i) {
    int r = lr + i * 4;
    out[(size_t)(c0 + r) * K + r0 + lc] = f2bf(t[lc][r]);
  }
}

__global__ void k_bias_concat(const float* __restrict__ bq, const float* __restrict__ bk,
                              const float* __restrict__ bv, float* __restrict__ out) {
  int i = blockIdx.x * 256 + threadIdx.x;
  if (i < NQKV) out[i] = (i < 2048) ? bq[i] : (i < NQK ? bk[i - 2048] : bv[i - NQK]);
}

// ---------------- GEMM: C(MxN) = A(MxK) * Bt(NxK)^T + bias  (R8-proven) ----------
// OMODE 0: Q columns (colg < 2048) are pre-scaled by C_SL2 (consumed only by attn QK^T).
__device__ __forceinline__ void stage_tile(const u16* __restrict__ G, int ldg, int row0, int kt,
                                           u16* lbase, int wid, int lane) {
#pragma unroll
  for (int i = 0; i < 4; ++i) {
    int c   = (wid * 4 + i) * 64 + lane;
    int row = c >> 3, cin = c & 7;
    int cs  = cin ^ (row & 7);  // source pre-swizzle (rule #21)
    const u16* g = G + (size_t)(row0 + row) * ldg + kt * 64 + cs * 8;
    gload16(g, (char*)lbase + (wid * 4 + i) * 1024);
  }
}

template <int OMODE>
__global__ __launch_bounds__(256)
void k_gemm(const u16* __restrict__ A, const u16* __restrict__ Bt,
            const float* __restrict__ bias, void* __restrict__ Cout,
            u16* __restrict__ vt, int M, int N, int K) {
  __shared__ u16 lA[2][128 * 64];
  __shared__ u16 lB[2][128 * 64];
  const int tid = threadIdx.x, lane = tid & 63, wid = tid >> 6;
  const int wm = wid >> 1, wn = wid & 1;
  const int tm = blockIdx.x, tn = blockIdx.y;
  const int nk = K >> 6;

  stage_tile(A, K, tm * 128, 0, lA[0], wid, lane);
  stage_tile(Bt, K, tn * 128, 0, lB[0], wid, lane);
  __syncthreads();

  floatx4 acc[4][4] = {};
  int buf = 0;
  for (int kt = 0; kt < nk; ++kt) {
    if (kt + 1 < nk) {
      stage_tile(A, K, tm * 128, kt + 1, lA[buf ^ 1], wid, lane);
      stage_tile(Bt, K, tn * 128, kt + 1, lB[buf ^ 1], wid, lane);
    }
    const char* pa = (const char*)&lA[buf][0];
    const char* pb = (const char*)&lB[buf][0];
#pragma unroll
    for (int kk = 0; kk < 2; ++kk) {
      bf16x8 af[4], bfr[4];
      int gch = kk * 4 + (lane >> 4);
#pragma unroll
      for (int f = 0; f < 4; ++f) {
        int ra = wm * 64 + f * 16 + (lane & 15);
        af[f]  = *(const bf16x8*)(pa + ra * 128 + ((gch ^ (ra & 7)) << 4));
        int rb = wn * 64 + f * 16 + (lane & 15);
        bfr[f] = *(const bf16x8*)(pb + rb * 128 + ((gch ^ (rb & 7)) << 4));
      }
      __builtin_amdgcn_s_setprio(1);
#pragma unroll
      for (int fm = 0; fm < 4; ++fm)
#pragma unroll
        for (int fn = 0; fn < 4; ++fn)
          acc[fm][fn] = __builtin_amdgcn_mfma_f32_16x16x32_bf16(af[fm], bfr[fn], acc[fm][fn], 0, 0, 0);
      __builtin_amdgcn_s_setprio(0);
    }
    __syncthreads();
    buf ^= 1;
  }

#pragma unroll
  for (int fm = 0; fm < 4; ++fm)
#pragma unroll
    for (int fn = 0; fn < 4; ++fn)
#pragma unroll
      for (int r = 0; r < 4; ++r) {
        int rowg = tm * 128 + wm * 64 + fm * 16 + (lane >> 4) * 4 + r;
        int colg = tn * 128 + wn * 64 + fn * 16 + (lane & 15);
        float v = acc[fm][fn][r] + bias[colg];
        if constexpr (OMODE == 1) {
          ((float*)Cout)[(size_t)rowg * N + colg] = v;
        } else {
          if (colg < 2048) {
            ((u16*)Cout)[(size_t)rowg * N + colg] = f2bf(v * C_SL2);  // Q pre-scale
          } else if (colg < NQK) {
            ((u16*)Cout)[(size_t)rowg * N + colg] = f2bf(v);
          } else {  // V: store transposed vt[b][d][s]
            int d = colg - NQK;
            int bg = rowg >> 11, s = rowg & 2047;
            vt[((size_t)bg * HD + d) * S_LEN + s] = f2bf(v);
          }
        }
      }
}

// ---------------- flash attention (8-wave, swapped-operand, KVBLK=128, mask C-init) ----
// grid (S/32, 2, B); 512 threads = 8 waves; wave w = head hg*8+w, all on same 32 q-rows.
// K tile 128x128 (256B rows), Vt tile 128x128, mask 32x128 bf16 (pre-scaled by LOG2E).
// Swizzle: chunk ^ (row & 15) on all three tiles -> 2-way max bank aliasing (free, m136).
// Scores come straight out of the QK MFMA: Q carries scale*log2e; mask is the C-init.
__device__ __forceinline__ void stage_kv128(const u16* __restrict__ qkv, const u16* __restrict__ vt,
                                            int b, int kt, u16* lK, u16* lV, int wid, int lane) {
#pragma unroll
  for (int i = 0; i < 4; ++i) {
    int seg = wid * 4 + i;             // 0..31, 1KB each
    int r = seg * 4 + (lane >> 4);     // row 0..127
    int cin = lane & 15;
    int cs = cin ^ (r & 15);           // source pre-swizzle (rule #21)
    const u16* gk = qkv + (size_t)(b * S_LEN + kt * 128 + r) * NQKV + 2048 + cs * 8;
    gload16(gk, (char*)lK + seg * 1024);
    const u16* gv = vt + ((size_t)b * HD + r) * S_LEN + kt * 128 + cs * 8;
    gload16(gv, (char*)lV + seg * 1024);
  }
}

// mask tile -> bf16 LDS pre-scaled by LOG2E; 32 rows x 256B, 16B chunks, 16-deep XOR
__device__ __forceinline__ void mask_write128(u16* lMb, int mq, int mc, floatx4 m0, floatx4 m1) {
  intx4 w;
  w[0] = cvtpk(m0[0] * LOG2E, m0[1] * LOG2E);
  w[1] = cvtpk(m0[2] * LOG2E, m0[3] * LOG2E);
  w[2] = cvtpk(m1[0] * LOG2E, m1[1] * LOG2E);
  w[3] = cvtpk(m1[2] * LOG2E, m1[3] * LOG2E);
  *(intx4*)((char*)lMb + mq * 256 + ((mc ^ (mq & 15)) << 4)) = w;
}

__global__ __launch_bounds__(512)
void k_attn(const u16* __restrict__ qkv, const u16* __restrict__ vt,
            const float* __restrict__ mask, u16* __restrict__ attn) {
  __shared__ __align__(16) u16 lK[2][128 * 128];   // 64KB
  __shared__ __align__(16) u16 lV[2][128 * 128];   // 64KB
  __shared__ __align__(16) u16 lMb[2][32 * 128];   // 16KB
  const int tid = threadIdx.x, lane = tid & 63, wid = tid >> 6;
  const int qt = blockIdx.x, hg = blockIdx.y, b = blockIdx.z;
  const int h = hg * 8 + wid;
  const int q = lane & 31, h5 = lane >> 5;

  // hoist Q (B-frag: col=q, d = cs*16 + h5*8 + idx); Q already scaled by C_SL2
  bf16x8 qf[8];
  const size_t qrow = (size_t)(b * S_LEN + qt * 32 + q);
#pragma unroll
  for (int cs = 0; cs < 8; ++cs)
    qf[cs] = *(const bf16x8*)(qkv + qrow * NQKV + h * HD + cs * 16 + h5 * 8);

  // hoisted LDS byte offsets (loop-invariant)
  const int qb = q * 256;
  int offK[8], offVc[8], offM[16];
#pragma unroll
  for (int cs = 0; cs < 8; ++cs)
    offK[cs] = qb + (((cs * 2 + h5) ^ (q & 15)) << 4);
#pragma unroll
  for (int hf = 0; hf < 2; ++hf)
#pragma unroll
    for (int ks = 0; ks < 4; ++ks)
      offVc[hf * 4 + ks] = (((hf * 8 + ks * 2 + h5) ^ (q & 15)) << 4);
#pragma unroll
  for (int c = 0; c < 16; ++c)
    offM[c] = qb + ((c ^ (q & 15)) << 4) + h5 * 8;

  float m_ = -1e30f, l_ = 0.f;   // log2-domain running max / sum
  floatx16 acco[4] = {};         // O^T: col=q (lane-local), row = d

  // mask stage helpers
  const int mq = tid >> 4, mc = tid & 15;
  const float* mrow = mask + (size_t)b * S_LEN * S_LEN + (size_t)(qt * 32 + mq) * S_LEN + mc * 8;

  // prologue: stage kt=0
  stage_kv128(qkv, vt, b, 0, lK[0], lV[0], wid, lane);
  {
    floatx4 m0 = *(const floatx4*)(mrow);
    floatx4 m1 = *(const floatx4*)(mrow + 4);
    mask_write128(&lMb[0][0], mq, mc, m0, m1);
  }
  __syncthreads();

  int buf = 0;
  for (int kt = 0; kt < NT2; ++kt) {
    floatx4 mr0, mr1;
    if (kt + 1 < NT2) {
      stage_kv128(qkv, vt, b, kt + 1, lK[buf ^ 1], lV[buf ^ 1], wid, lane);
      mr0 = *(const floatx4*)(mrow + (size_t)(kt + 1) * 128);
      mr1 = *(const floatx4*)(mrow + (size_t)(kt + 1) * 128 + 4);
    }
    const char* pKb = (const char*)&lK[buf][0];
    const char* pVb = (const char*)&lV[buf][0];
    const char* pMb = (const char*)&lMb[buf][0];

#pragma unroll
    for (int hf = 0; hf < 2; ++hf) {
      // ---- C-init: accs start at mask*log2e (acc reg rg*4+t <-> key 32kb+8rg+4h5+t) ----
      floatx16 accs0, accs1;
#pragma unroll
      for (int kb = 0; kb < 2; ++kb)
#pragma unroll
        for (int rg = 0; rg < 4; ++rg) {
          ushort4 mu = *(const ushort4*)(pMb + offM[hf * 8 + kb * 4 + rg]);
          if (kb == 0) {
            accs0[rg * 4 + 0] = bf2f(mu.x);
            accs0[rg * 4 + 1] = bf2f(mu.y);
            accs0[rg * 4 + 2] = bf2f(mu.z);
            accs0[rg * 4 + 3] = bf2f(mu.w);
          } else {
            accs1[rg * 4 + 0] = bf2f(mu.x);
            accs1[rg * 4 + 1] = bf2f(mu.y);
            accs1[rg * 4 + 2] = bf2f(mu.z);
            accs1[rg * 4 + 3] = bf2f(mu.w);
          }
        }

      // ---- QK^T swapped: accs = K * (Q*c_sl2)^T + mask*log2e = scores (log2 domain) ----
      const char* pK = pKb + hf * 16384;
      __builtin_amdgcn_s_setprio(1);
#pragma unroll
      for (int cs = 0; cs < 8; ++cs) {
        bf16x8 kf0 = *(const bf16x8*)(pK + offK[cs]);
        bf16x8 kf1 = *(const bf16x8*)(pK + 8192 + offK[cs]);
        accs0 = mfma32(kf0, qf[cs], accs0, 0, 0, 0);
        accs1 = mfma32(kf1, qf[cs], accs1, 0, 0, 0);
      }
      __builtin_amdgcn_s_setprio(0);

      // ---- online softmax: max via v_max3 triples, exp direct from accs ----
      float pm0 = -1e30f, pm1 = -1e30f, pm2 = -1e30f, pm3 = -1e30f;
#pragma unroll
      for (int r = 0; r < 16; r += 4) {
        pm0 = fmaxf(fmaxf(accs0[r + 0], accs0[r + 1]), pm0);
        pm1 = fmaxf(fmaxf(accs0[r + 2], accs0[r + 3]), pm1);
        pm2 = fmaxf(fmaxf(accs1[r + 0], accs1[r + 1]), pm2);
        pm3 = fmaxf(fmaxf(accs1[r + 2], accs1[r + 3]), pm3);
      }
      float rowm = red_max32(fmaxf(fmaxf(pm0, pm1), fmaxf(pm2, pm3)));

      // defer-max (T13): only rescale when max grows by > 8/ln2 (log2 units)
      if (__any(rowm > m_ + 11.5415603f)) {
        float mn = fmaxf(m_, rowm);
        float al = fexp2(m_ - mn);
        m_ = mn;
        l_ *= al;
#pragma unroll
        for (int dt = 0; dt < 4; ++dt) acco[dt] *= al;
      }
      float pr[32];
      float ps0 = 0.f, ps1 = 0.f, ps2 = 0.f, ps3 = 0.f;
#pragma unroll
      for (int i = 0; i < 16; i += 4) {
        float e0 = fexp2(accs0[i + 0] - m_); pr[i + 0] = e0; ps0 += e0;
        float e1 = fexp2(accs0[i + 1] - m_); pr[i + 1] = e1; ps1 += e1;
        float e2 = fexp2(accs0[i + 2] - m_); pr[i + 2] = e2; ps2 += e2;
        float e3 = fexp2(accs0[i + 3] - m_); pr[i + 3] = e3; ps3 += e3;
      }
#pragma unroll
      for (int i = 0; i < 16; i += 4) {
        float e0 = fexp2(accs1[i + 0] - m_); pr[16 + i + 0] = e0; ps0 += e0;
        float e1 = fexp2(accs1[i + 1] - m_); pr[16 + i + 1] = e1; ps1 += e1;
        float e2 = fexp2(accs1[i + 2] - m_); pr[16 + i + 2] = e2; ps2 += e2;
        float e3 = fexp2(accs1[i + 3] - m_); pr[16 + i + 3] = e3; ps3 += e3;
      }
      l_ += red_add32((ps0 + ps1) + (ps2 + ps3));

      // ---- pack P into PV B-fragments (cvt_pk + permlane32_swap, no LDS/DS) ----
      bf16x8 pf[4];
#pragma unroll
      for (int kb = 0; kb < 2; ++kb)
#pragma unroll
        for (int s = 0; s < 2; ++s) {
          int base = kb * 16 + s * 8;
          int A0 = cvtpk(pr[base + 0], pr[base + 1]);
          int A1 = cvtpk(pr[base + 2], pr[base + 3]);
          int B0 = cvtpk(pr[base + 4], pr[base + 5]);
          int B1 = cvtpk(pr[base + 6], pr[base + 7]);
          half_swap(A0, B0);
          half_swap(A1, B1);
          intx4 w;
          w[0] = A0; w[1] = A1; w[2] = B0; w[3] = B1;
          pf[kb * 2 + s] = __builtin_bit_cast(bf16x8, w);
        }

      // ---- PV swapped: acco += Vt * P^T = O^T (col = q) ----
      __builtin_amdgcn_s_setprio(1);
#pragma unroll
      for (int dt = 0; dt < 4; ++dt)
#pragma unroll
        for (int ks = 0; ks < 4; ++ks) {
          bf16x8 vf = *(const bf16x8*)(pVb + dt * 8192 + qb + offVc[hf * 4 + ks]);
          acco[dt] = mfma32(vf, pf[ks], acco[dt], 0, 0, 0);
        }
      __builtin_amdgcn_s_setprio(0);
    }

    if (kt + 1 < NT2)
      mask_write128(&lMb[buf ^ 1][0], mq, mc, mr0, mr1);
    __syncthreads();
    buf ^= 1;
  }

  // ---- epilogue: attn[q][h*HD + d] = O/l ----
  float inv = 1.0f / l_;
  u16* obase = attn + qrow * DIMSZ + h * HD;
#pragma unroll
  for (int dt = 0; dt < 4; ++dt)
#pragma unroll
    for (int rg = 0; rg < 4; ++rg) {
      int d0 = dt * 32 + rg * 8 + h5 * 4;
      ushort4 st;
      st.x = f2bf(acco[dt][rg * 4 + 0] * inv);
      st.y = f2bf(acco[dt][rg * 4 + 1] * inv);
      st.z = f2bf(acco[dt][rg * 4 + 2] * inv);
      st.w = f2bf(acco[dt][rg * 4 + 3] * inv);
      *(ushort4*)(obase + d0) = st;
    }
}

// ---------------- launch ----------------
extern "C" void kernel_launch(void* const* d_in, const int* in_sizes, int n_in,
                              void* d_out, int out_size, void* d_ws, size_t ws_size,
                              hipStream_t stream) {
  const float* hidden = (const float*)d_in[0];
  const float* mask   = (const float*)d_in[1];
  const float* wq = (const float*)d_in[2];
  const float* bq = (const float*)d_in[3];
  const float* wk = (const float*)d_in[4];
  const float* bk = (const float*)d_in[5];
  const float* wv = (const float*)d_in[6];
  const float* bv = (const float*)d_in[7];
  const float* wo = (const float*)d_in[8];
  const float* bo = (const float*)d_in[9];
  float* out = (float*)d_out;

  // workspace layout (total ~71.3 MB)
  char* ws = (char*)d_ws;
  u16*   hb    = (u16*)(ws);                    // hidden bf16: 4096x2048
  u16*   wqkvT = (u16*)(ws + 16777216);         // [wq^T; wk^T; wv^T]: 2304x2048
  u16*   woT   = (u16*)(ws + 26214400);         // wo^T: 2048x2048
  float* bqkv  = (float*)(ws + 34603008);       // 2304 f32
  u16*   qkv   = (u16*)(ws + 34612224);         // 4096x2304 (Q cols pre-scaled by C_SL2)
  u16*   vt    = (u16*)(ws + 53486592);         // 2 x 128 x 2048
  u16*   attn  = (u16*)(ws + 54535168);         // 4096x2048

  k_cvt_bf16<<<dim3(8192), dim3(256), 0, stream>>>(hidden, hb, 4096 * 2048 / 4);
  k_transpose_qkv<<<dim3(36, 32), dim3(256), 0, stream>>>(wq, wk, wv, wqkvT, 2048);
  k_transpose_bf16<<<dim3(32, 32), dim3(256), 0, stream>>>(wo, woT, 2048, 2048);
  k_bias_concat<<<dim3(9), dim3(256), 0, stream>>>(bq, bk, bv, bqkv);

  k_gemm<0><<<dim3(32, 18), dim3(256), 0, stream>>>(hb, wqkvT, bqkv, (void*)qkv, vt, 4096, NQKV, 2048);
  k_attn<<<dim3(64, 2, 2), dim3(512), 0, stream>>>(qkv, vt, mask, attn);
  k_gemm<1><<<dim3(32, 16), dim3(256), 0, stream>>>(attn, woT, bo, (void*)out, (u16*)nullptr, 4096, 2048, 2048);
}

// Round 14
// 192.490 us; speedup vs baseline: 1.1485x; 1.0372x over previous
//
#include <hip/hip_runtime.h>
#include <hip/hip_bf16.h>
#include <stdint.h>

#define S_LEN 2048
#define DIMSZ 2048
#define NH    16
#define HD    128
#define NQK   2176   // Q cols (2048) + K cols (128); V cols start here
#define NQKV  2304
#define NT2   (S_LEN / 128)

typedef short  bf16x8  __attribute__((ext_vector_type(8)));
typedef float  floatx4 __attribute__((ext_vector_type(4)));
typedef float  floatx16 __attribute__((ext_vector_type(16)));
typedef int    intx4   __attribute__((ext_vector_type(4)));
typedef unsigned short u16;

#define mfma32 __builtin_amdgcn_mfma_f32_32x32x16_bf16
#define LOG2E 1.4426950408889634f
#define C_SL2 (0.08838834764831845f * LOG2E)   // 1/sqrt(128) * log2(e)

// round-to-nearest-even f32 -> bf16 bits
__device__ __forceinline__ u16 f2bf(float x) {
  unsigned int u = __builtin_bit_cast(unsigned int, x);
  u = (u + 0x7FFFu + ((u >> 16) & 1u)) >> 16;
  return (u16)u;
}
__device__ __forceinline__ float bf2f(unsigned int bits) {
  return __builtin_bit_cast(float, bits << 16);
}

// v_cvt_pk_bf16_f32: word = (bf16(hi)<<16) | bf16(lo)   (plain VALU, no hazard)
__device__ __forceinline__ int cvtpk(float lo, float hi) {
  int r;
  asm("v_cvt_pk_bf16_f32 %0, %1, %2" : "=v"(r) : "v"(lo), "v"(hi));
  return r;
}

// 2^x — builtin so the compiler handles the TRANS wait-state hazard
#if __has_builtin(__builtin_amdgcn_exp2f)
__device__ __forceinline__ float fexp2(float x) { return __builtin_amdgcn_exp2f(x); }
#else
__device__ __forceinline__ float fexp2(float x) { return exp2f(x); }
#endif

// half swap via BUILTIN (hazard-modeled): a'[32:63]=b[0:31], b'[0:31]=a[32:63]
#if __has_builtin(__builtin_amdgcn_permlane32_swap)
__device__ __forceinline__ void half_swap(int& a, int& b) {
  auto r = __builtin_amdgcn_permlane32_swap(a, b, false, false);
  a = (int)r[0]; b = (int)r[1];
}
__device__ __forceinline__ float red_max32(float x) {
  int xi = __builtin_bit_cast(int, x);
  auto r = __builtin_amdgcn_permlane32_swap(xi, xi, false, false);
  return fmaxf(__builtin_bit_cast(float, (int)r[0]), __builtin_bit_cast(float, (int)r[1]));
}
__device__ __forceinline__ float red_add32(float x) {
  int xi = __builtin_bit_cast(int, x);
  auto r = __builtin_amdgcn_permlane32_swap(xi, xi, false, false);
  return __builtin_bit_cast(float, (int)r[0]) + __builtin_bit_cast(float, (int)r[1]);
}
#else
__device__ __forceinline__ void half_swap(int& a, int& b) {
  int as = __shfl_xor(a, 32);
  int bs = __shfl_xor(b, 32);
  int lane = threadIdx.x & 63;
  int na = (lane < 32) ? a : bs;
  int nb = (lane < 32) ? as : b;
  a = na; b = nb;
}
__device__ __forceinline__ float red_max32(float x) { return fmaxf(x, __shfl_xor(x, 32)); }
__device__ __forceinline__ float red_add32(float x) { return x + __shfl_xor(x, 32); }
#endif

// async global->LDS, 16 bytes per lane; LDS dest wave-uniform base (+lane*16 by HW)
__device__ __forceinline__ void gload16(const void* g, void* l) {
  __builtin_amdgcn_global_load_lds(
      reinterpret_cast<const __attribute__((address_space(1))) void*>(reinterpret_cast<uintptr_t>(g)),
      reinterpret_cast<__attribute__((address_space(3))) void*>(reinterpret_cast<uintptr_t>(l)),
      16, 0, 0);
}

// ---------------- merged prep: cvt + both transposes + bias concat ----------------
// flat grid: [0,8192) cvt | [8192,9344) qkvT (36x32) | [9344,10368) woT (32x32) | [10368,10377) bias
__global__ __launch_bounds__(256)
void k_prep(const float* __restrict__ hidden, u16* __restrict__ hb,
            const float* __restrict__ wq, const float* __restrict__ wk,
            const float* __restrict__ wv, u16* __restrict__ wqkvT,
            const float* __restrict__ wo, u16* __restrict__ woT,
            const float* __restrict__ bq, const float* __restrict__ bk,
            const float* __restrict__ bv, float* __restrict__ bqkv) {
  __shared__ float t[64][65];
  int bid = blockIdx.x;
  int tid = threadIdx.x;
  if (bid < 8192) {                      // hidden f32 -> bf16 (4 elems/thread)
    int i = bid * 256 + tid;
    float4 v = ((const float4*)hidden)[i];
    ushort4 o;
    o.x = f2bf(v.x); o.y = f2bf(v.y); o.z = f2bf(v.z); o.w = f2bf(v.w);
    ((ushort4*)hb)[i] = o;
    return;
  }
  bid -= 8192;
  const float* src;
  u16* dst;
  int N, scol0, orow0, r0;
  if (bid < 1152) {                      // wq|wk|wv transpose -> wqkvT
    orow0 = (bid % 36) * 64;
    r0 = (bid / 36) * 64;
    if (orow0 < 2048)      { src = wq; N = 2048; scol0 = orow0; }
    else if (orow0 < NQK)  { src = wk; N = 128;  scol0 = orow0 - 2048; }
    else                   { src = wv; N = 128;  scol0 = orow0 - NQK; }
    dst = wqkvT;
  } else if (bid < 1152 + 1024) {        // wo transpose -> woT
    int b2 = bid - 1152;
    orow0 = (b2 % 32) * 64;
    r0 = (b2 / 32) * 64;
    src = wo; N = 2048; scol0 = orow0;
    dst = woT;
  } else {                               // bias concat (9 blocks)
    int i = (bid - 1152 - 1024) * 256 + tid;
    if (i < NQKV) bqkv[i] = (i < 2048) ? bq[i] : (i < NQK ? bk[i - 2048] : bv[i - NQK]);
    return;
  }
  int lr = tid >> 6, lc = tid & 63;
#pragma unroll
  for (int i = 0; i < 16; ++i) {
    int r = lr + i * 4;
    t[r][lc] = src[(size_t)(r0 + r) * N + scol0 + lc];
  }
  __syncthreads();
#pragma unroll
  for (int i = 0; i < 16; ++i) {
    int r = lr + i * 4;
    dst[(size_t)(orow0 + r) * 2048 + r0 + lc] = f2bf(t[lc][r]);
  }
}

// ---------------- GEMM: C(MxN) = A(MxK) * Bt(NxK)^T + bias  (R8-proven) ----------
// OMODE 0: Q columns (colg < 2048) are pre-scaled by C_SL2 (consumed only by attn QK^T).
__device__ __forceinline__ void stage_tile(const u16* __restrict__ G, int ldg, int row0, int kt,
                                           u16* lbase, int wid, int lane) {
#pragma unroll
  for (int i = 0; i < 4; ++i) {
    int c   = (wid * 4 + i) * 64 + lane;
    int row = c >> 3, cin = c & 7;
    int cs  = cin ^ (row & 7);  // source pre-swizzle (rule #21)
    const u16* g = G + (size_t)(row0 + row) * ldg + kt * 64 + cs * 8;
    gload16(g, (char*)lbase + (wid * 4 + i) * 1024);
  }
}

template <int OMODE>
__global__ __launch_bounds__(256)
void k_gemm(const u16* __restrict__ A, const u16* __restrict__ Bt,
            const float* __restrict__ bias, void* __restrict__ Cout,
            u16* __restrict__ vt, int M, int N, int K) {
  __shared__ u16 lA[2][128 * 64];
  __shared__ u16 lB[2][128 * 64];
  const int tid = threadIdx.x, lane = tid & 63, wid = tid >> 6;
  const int wm = wid >> 1, wn = wid & 1;
  const int tm = blockIdx.x, tn = blockIdx.y;
  const int nk = K >> 6;

  stage_tile(A, K, tm * 128, 0, lA[0], wid, lane);
  stage_tile(Bt, K, tn * 128, 0, lB[0], wid, lane);
  __syncthreads();

  floatx4 acc[4][4] = {};
  int buf = 0;
  for (int kt = 0; kt < nk; ++kt) {
    if (kt + 1 < nk) {
      stage_tile(A, K, tm * 128, kt + 1, lA[buf ^ 1], wid, lane);
      stage_tile(Bt, K, tn * 128, kt + 1, lB[buf ^ 1], wid, lane);
    }
    const char* pa = (const char*)&lA[buf][0];
    const char* pb = (const char*)&lB[buf][0];
#pragma unroll
    for (int kk = 0; kk < 2; ++kk) {
      bf16x8 af[4], bfr[4];
      int gch = kk * 4 + (lane >> 4);
#pragma unroll
      for (int f = 0; f < 4; ++f) {
        int ra = wm * 64 + f * 16 + (lane & 15);
        af[f]  = *(const bf16x8*)(pa + ra * 128 + ((gch ^ (ra & 7)) << 4));
        int rb = wn * 64 + f * 16 + (lane & 15);
        bfr[f] = *(const bf16x8*)(pb + rb * 128 + ((gch ^ (rb & 7)) << 4));
      }
      __builtin_amdgcn_s_setprio(1);
#pragma unroll
      for (int fm = 0; fm < 4; ++fm)
#pragma unroll
        for (int fn = 0; fn < 4; ++fn)
          acc[fm][fn] = __builtin_amdgcn_mfma_f32_16x16x32_bf16(af[fm], bfr[fn], acc[fm][fn], 0, 0, 0);
      __builtin_amdgcn_s_setprio(0);
    }
    __syncthreads();
    buf ^= 1;
  }

#pragma unroll
  for (int fm = 0; fm < 4; ++fm)
#pragma unroll
    for (int fn = 0; fn < 4; ++fn)
#pragma unroll
      for (int r = 0; r < 4; ++r) {
        int rowg = tm * 128 + wm * 64 + fm * 16 + (lane >> 4) * 4 + r;
        int colg = tn * 128 + wn * 64 + fn * 16 + (lane & 15);
        float v = acc[fm][fn][r] + bias[colg];
        if constexpr (OMODE == 1) {
          ((float*)Cout)[(size_t)rowg * N + colg] = v;
        } else {
          if (colg < 2048) {
            ((u16*)Cout)[(size_t)rowg * N + colg] = f2bf(v * C_SL2);  // Q pre-scale
          } else if (colg < NQK) {
            ((u16*)Cout)[(size_t)rowg * N + colg] = f2bf(v);
          } else {  // V: store transposed vt[b][d][s]
            int d = colg - NQK;
            int bg = rowg >> 11, s = rowg & 2047;
            vt[((size_t)bg * HD + d) * S_LEN + s] = f2bf(v);
          }
        }
      }
}

// ---------------- flash attention (8-wave, swapped-operand, KVBLK=128, wide QK phase) ----
// grid (S/32, 2, B); 512 threads = 8 waves; wave w = head hg*8+w, all on same 32 q-rows.
// Per kt: C-init all 4 score accs from mask -> 32-MFMA QK cluster (both halves) ->
// SM0 -> PV0 -> SM1 -> PV1.  Wider MFMA phases increase inter-wave skew so the
// SIMD's second wave runs its softmax VALU under the first wave's MFMA occupancy.
__device__ __forceinline__ void stage_kv128(const u16* __restrict__ qkv, const u16* __restrict__ vt,
                                            int b, int kt, u16* lK, u16* lV, int wid, int lane) {
#pragma unroll
  for (int i = 0; i < 4; ++i) {
    int seg = wid * 4 + i;             // 0..31, 1KB each
    int r = seg * 4 + (lane >> 4);     // row 0..127
    int cin = lane & 15;
    int cs = cin ^ (r & 15);           // source pre-swizzle (rule #21)
    const u16* gk = qkv + (size_t)(b * S_LEN + kt * 128 + r) * NQKV + 2048 + cs * 8;
    gload16(gk, (char*)lK + seg * 1024);
    const u16* gv = vt + ((size_t)b * HD + r) * S_LEN + kt * 128 + cs * 8;
    gload16(gv, (char*)lV + seg * 1024);
  }
}

// mask tile -> bf16 LDS pre-scaled by LOG2E; 32 rows x 256B, 16B chunks, 16-deep XOR
__device__ __forceinline__ void mask_write128(u16* lMb, int mq, int mc, floatx4 m0, floatx4 m1) {
  intx4 w;
  w[0] = cvtpk(m0[0] * LOG2E, m0[1] * LOG2E);
  w[1] = cvtpk(m0[2] * LOG2E, m0[3] * LOG2E);
  w[2] = cvtpk(m1[0] * LOG2E, m1[1] * LOG2E);
  w[3] = cvtpk(m1[2] * LOG2E, m1[3] * LOG2E);
  *(intx4*)((char*)lMb + mq * 256 + ((mc ^ (mq & 15)) << 4)) = w;
}

__global__ __launch_bounds__(512)
void k_attn(const u16* __restrict__ qkv, const u16* __restrict__ vt,
            const float* __restrict__ mask, u16* __restrict__ attn) {
  __shared__ __align__(16) u16 lK[2][128 * 128];   // 64KB
  __shared__ __align__(16) u16 lV[2][128 * 128];   // 64KB
  __shared__ __align__(16) u16 lMb[2][32 * 128];   // 16KB
  const int tid = threadIdx.x, lane = tid & 63, wid = tid >> 6;
  const int qt = blockIdx.x, hg = blockIdx.y, b = blockIdx.z;
  const int h = hg * 8 + wid;
  const int q = lane & 31, h5 = lane >> 5;

  // hoist Q (B-frag: col=q, d = cs*16 + h5*8 + idx); Q already scaled by C_SL2
  bf16x8 qf[8];
  const size_t qrow = (size_t)(b * S_LEN + qt * 32 + q);
#pragma unroll
  for (int cs = 0; cs < 8; ++cs)
    qf[cs] = *(const bf16x8*)(qkv + qrow * NQKV + h * HD + cs * 16 + h5 * 8);

  // hoisted LDS byte offsets (loop-invariant)
  const int qb = q * 256;
  int offK[8], offVc[8], offM[16];
#pragma unroll
  for (int cs = 0; cs < 8; ++cs)
    offK[cs] = qb + (((cs * 2 + h5) ^ (q & 15)) << 4);
#pragma unroll
  for (int hf = 0; hf < 2; ++hf)
#pragma unroll
    for (int ks = 0; ks < 4; ++ks)
      offVc[hf * 4 + ks] = (((hf * 8 + ks * 2 + h5) ^ (q & 15)) << 4);
#pragma unroll
  for (int c = 0; c < 16; ++c)
    offM[c] = qb + ((c ^ (q & 15)) << 4) + h5 * 8;

  float m_ = -1e30f, l_ = 0.f;   // log2-domain running max / sum
  floatx16 acco[4] = {};         // O^T: col=q (lane-local), row = d

  // mask stage helpers
  const int mq = tid >> 4, mc = tid & 15;
  const float* mrow = mask + (size_t)b * S_LEN * S_LEN + (size_t)(qt * 32 + mq) * S_LEN + mc * 8;

  // prologue: stage kt=0
  stage_kv128(qkv, vt, b, 0, lK[0], lV[0], wid, lane);
  {
    floatx4 m0 = *(const floatx4*)(mrow);
    floatx4 m1 = *(const floatx4*)(mrow + 4);
    mask_write128(&lMb[0][0], mq, mc, m0, m1);
  }
  __syncthreads();

  int buf = 0;
  for (int kt = 0; kt < NT2; ++kt) {
    floatx4 mr0, mr1;
    if (kt + 1 < NT2) {
      stage_kv128(qkv, vt, b, kt + 1, lK[buf ^ 1], lV[buf ^ 1], wid, lane);
      mr0 = *(const floatx4*)(mrow + (size_t)(kt + 1) * 128);
      mr1 = *(const floatx4*)(mrow + (size_t)(kt + 1) * 128 + 4);
    }
    const char* pKb = (const char*)&lK[buf][0];
    const char* pVb = (const char*)&lV[buf][0];
    const char* pMb = (const char*)&lMb[buf][0];

    // ---- C-init all four score accumulators from mask*log2e ----
    floatx16 aA0, aA1, aB0, aB1;
#pragma unroll
    for (int rg = 0; rg < 4; ++rg) {
      ushort4 mu;
      mu = *(const ushort4*)(pMb + offM[0 * 8 + 0 * 4 + rg]);
      aA0[rg * 4 + 0] = bf2f(mu.x); aA0[rg * 4 + 1] = bf2f(mu.y);
      aA0[rg * 4 + 2] = bf2f(mu.z); aA0[rg * 4 + 3] = bf2f(mu.w);
      mu = *(const ushort4*)(pMb + offM[0 * 8 + 1 * 4 + rg]);
      aA1[rg * 4 + 0] = bf2f(mu.x); aA1[rg * 4 + 1] = bf2f(mu.y);
      aA1[rg * 4 + 2] = bf2f(mu.z); aA1[rg * 4 + 3] = bf2f(mu.w);
      mu = *(const ushort4*)(pMb + offM[1 * 8 + 0 * 4 + rg]);
      aB0[rg * 4 + 0] = bf2f(mu.x); aB0[rg * 4 + 1] = bf2f(mu.y);
      aB0[rg * 4 + 2] = bf2f(mu.z); aB0[rg * 4 + 3] = bf2f(mu.w);
      mu = *(const ushort4*)(pMb + offM[1 * 8 + 1 * 4 + rg]);
      aB1[rg * 4 + 0] = bf2f(mu.x); aB1[rg * 4 + 1] = bf2f(mu.y);
      aB1[rg * 4 + 2] = bf2f(mu.z); aB1[rg * 4 + 3] = bf2f(mu.w);
    }

    // ---- QK^T both halves: one 32-MFMA cluster ----
    __builtin_amdgcn_s_setprio(1);
#pragma unroll
    for (int cs = 0; cs < 8; ++cs) {
      bf16x8 k0 = *(const bf16x8*)(pKb + offK[cs]);
      bf16x8 k1 = *(const bf16x8*)(pKb + 8192 + offK[cs]);
      bf16x8 k2 = *(const bf16x8*)(pKb + 16384 + offK[cs]);
      bf16x8 k3 = *(const bf16x8*)(pKb + 24576 + offK[cs]);
      aA0 = mfma32(k0, qf[cs], aA0, 0, 0, 0);
      aA1 = mfma32(k1, qf[cs], aA1, 0, 0, 0);
      aB0 = mfma32(k2, qf[cs], aB0, 0, 0, 0);
      aB1 = mfma32(k3, qf[cs], aB1, 0, 0, 0);
    }
    __builtin_amdgcn_s_setprio(0);

    // ================= half 0: softmax + PV =================
    {
      float pm0 = -1e30f, pm1 = -1e30f, pm2 = -1e30f, pm3 = -1e30f;
#pragma unroll
      for (int r = 0; r < 16; r += 4) {
        pm0 = fmaxf(fmaxf(aA0[r + 0], aA0[r + 1]), pm0);
        pm1 = fmaxf(fmaxf(aA0[r + 2], aA0[r + 3]), pm1);
        pm2 = fmaxf(fmaxf(aA1[r + 0], aA1[r + 1]), pm2);
        pm3 = fmaxf(fmaxf(aA1[r + 2], aA1[r + 3]), pm3);
      }
      float rowm = red_max32(fmaxf(fmaxf(pm0, pm1), fmaxf(pm2, pm3)));
      if (__any(rowm > m_ + 11.5415603f)) {
        float mn = fmaxf(m_, rowm);
        float al = fexp2(m_ - mn);
        m_ = mn;
        l_ *= al;
#pragma unroll
        for (int dt = 0; dt < 4; ++dt) acco[dt] *= al;
      }
      float pr[32];
      float ps0 = 0.f, ps1 = 0.f, ps2 = 0.f, ps3 = 0.f;
#pragma unroll
      for (int i = 0; i < 16; i += 4) {
        float e0 = fexp2(aA0[i + 0] - m_); pr[i + 0] = e0; ps0 += e0;
        float e1 = fexp2(aA0[i + 1] - m_); pr[i + 1] = e1; ps1 += e1;
        float e2 = fexp2(aA0[i + 2] - m_); pr[i + 2] = e2; ps2 += e2;
        float e3 = fexp2(aA0[i + 3] - m_); pr[i + 3] = e3; ps3 += e3;
      }
#pragma unroll
      for (int i = 0; i < 16; i += 4) {
        float e0 = fexp2(aA1[i + 0] - m_); pr[16 + i + 0] = e0; ps0 += e0;
        float e1 = fexp2(aA1[i + 1] - m_); pr[16 + i + 1] = e1; ps1 += e1;
        float e2 = fexp2(aA1[i + 2] - m_); pr[16 + i + 2] = e2; ps2 += e2;
        float e3 = fexp2(aA1[i + 3] - m_); pr[16 + i + 3] = e3; ps3 += e3;
      }
      l_ += red_add32((ps0 + ps1) + (ps2 + ps3));

      bf16x8 pf[4];
#pragma unroll
      for (int kb = 0; kb < 2; ++kb)
#pragma unroll
        for (int s = 0; s < 2; ++s) {
          int base = kb * 16 + s * 8;
          int A0 = cvtpk(pr[base + 0], pr[base + 1]);
          int A1 = cvtpk(pr[base + 2], pr[base + 3]);
          int B0 = cvtpk(pr[base + 4], pr[base + 5]);
          int B1 = cvtpk(pr[base + 6], pr[base + 7]);
          half_swap(A0, B0);
          half_swap(A1, B1);
          intx4 w;
          w[0] = A0; w[1] = A1; w[2] = B0; w[3] = B1;
          pf[kb * 2 + s] = __builtin_bit_cast(bf16x8, w);
        }

      __builtin_amdgcn_s_setprio(1);
#pragma unroll
      for (int dt = 0; dt < 4; ++dt)
#pragma unroll
        for (int ks = 0; ks < 4; ++ks) {
          bf16x8 vf = *(const bf16x8*)(pVb + dt * 8192 + qb + offVc[ks]);
          acco[dt] = mfma32(vf, pf[ks], acco[dt], 0, 0, 0);
        }
      __builtin_amdgcn_s_setprio(0);
    }

    // ================= half 1: softmax + PV =================
    {
      float pm0 = -1e30f, pm1 = -1e30f, pm2 = -1e30f, pm3 = -1e30f;
#pragma unroll
      for (int r = 0; r < 16; r += 4) {
        pm0 = fmaxf(fmaxf(aB0[r + 0], aB0[r + 1]), pm0);
        pm1 = fmaxf(fmaxf(aB0[r + 2], aB0[r + 3]), pm1);
        pm2 = fmaxf(fmaxf(aB1[r + 0], aB1[r + 1]), pm2);
        pm3 = fmaxf(fmaxf(aB1[r + 2], aB1[r + 3]), pm3);
      }
      float rowm = red_max32(fmaxf(fmaxf(pm0, pm1), fmaxf(pm2, pm3)));
      if (__any(rowm > m_ + 11.5415603f)) {
        float mn = fmaxf(m_, rowm);
        float al = fexp2(m_ - mn);
        m_ = mn;
        l_ *= al;
#pragma unroll
        for (int dt = 0; dt < 4; ++dt) acco[dt] *= al;
      }
      float pr[32];
      float ps0 = 0.f, ps1 = 0.f, ps2 = 0.f, ps3 = 0.f;
#pragma unroll
      for (int i = 0; i < 16; i += 4) {
        float e0 = fexp2(aB0[i + 0] - m_); pr[i + 0] = e0; ps0 += e0;
        float e1 = fexp2(aB0[i + 1] - m_); pr[i + 1] = e1; ps1 += e1;
        float e2 = fexp2(aB0[i + 2] - m_); pr[i + 2] = e2; ps2 += e2;
        float e3 = fexp2(aB0[i + 3] - m_); pr[i + 3] = e3; ps3 += e3;
      }
#pragma unroll
      for (int i = 0; i < 16; i += 4) {
        float e0 = fexp2(aB1[i + 0] - m_); pr[16 + i + 0] = e0; ps0 += e0;
        float e1 = fexp2(aB1[i + 1] - m_); pr[16 + i + 1] = e1; ps1 += e1;
        float e2 = fexp2(aB1[i + 2] - m_); pr[16 + i + 2] = e2; ps2 += e2;
        float e3 = fexp2(aB1[i + 3] - m_); pr[16 + i + 3] = e3; ps3 += e3;
      }
      l_ += red_add32((ps0 + ps1) + (ps2 + ps3));

      bf16x8 pf[4];
#pragma unroll
      for (int kb = 0; kb < 2; ++kb)
#pragma unroll
        for (int s = 0; s < 2; ++s) {
          int base = kb * 16 + s * 8;
          int A0 = cvtpk(pr[base + 0], pr[base + 1]);
          int A1 = cvtpk(pr[base + 2], pr[base + 3]);
          int B0 = cvtpk(pr[base + 4], pr[base + 5]);
          int B1 = cvtpk(pr[base + 6], pr[base + 7]);
          half_swap(A0, B0);
          half_swap(A1, B1);
          intx4 w;
          w[0] = A0; w[1] = A1; w[2] = B0; w[3] = B1;
          pf[kb * 2 + s] = __builtin_bit_cast(bf16x8, w);
        }

      __builtin_amdgcn_s_setprio(1);
#pragma unroll
      for (int dt = 0; dt < 4; ++dt)
#pragma unroll
        for (int ks = 0; ks < 4; ++ks) {
          bf16x8 vf = *(const bf16x8*)(pVb + dt * 8192 + qb + offVc[4 + ks]);
          acco[dt] = mfma32(vf, pf[ks], acco[dt], 0, 0, 0);
        }
      __builtin_amdgcn_s_setprio(0);
    }

    if (kt + 1 < NT2)
      mask_write128(&lMb[buf ^ 1][0], mq, mc, mr0, mr1);
    __syncthreads();
    buf ^= 1;
  }

  // ---- epilogue: attn[q][h*HD + d] = O/l ----
  float inv = 1.0f / l_;
  u16* obase = attn + qrow * DIMSZ + h * HD;
#pragma unroll
  for (int dt = 0; dt < 4; ++dt)
#pragma unroll
    for (int rg = 0; rg < 4; ++rg) {
      int d0 = dt * 32 + rg * 8 + h5 * 4;
      ushort4 st;
      st.x = f2bf(acco[dt][rg * 4 + 0] * inv);
      st.y = f2bf(acco[dt][rg * 4 + 1] * inv);
      st.z = f2bf(acco[dt][rg * 4 + 2] * inv);
      st.w = f2bf(acco[dt][rg * 4 + 3] * inv);
      *(ushort4*)(obase + d0) = st;
    }
}

// ---------------- launch ----------------
extern "C" void kernel_launch(void* const* d_in, const int* in_sizes, int n_in,
                              void* d_out, int out_size, void* d_ws, size_t ws_size,
                              hipStream_t stream) {
  const float* hidden = (const float*)d_in[0];
  const float* mask   = (const float*)d_in[1];
  const float* wq = (const float*)d_in[2];
  const float* bq = (const float*)d_in[3];
  const float* wk = (const float*)d_in[4];
  const float* bk = (const float*)d_in[5];
  const float* wv = (const float*)d_in[6];
  const float* bv = (const float*)d_in[7];
  const float* wo = (const float*)d_in[8];
  const float* bo = (const float*)d_in[9];
  float* out = (float*)d_out;

  // workspace layout (total ~71.3 MB)
  char* ws = (char*)d_ws;
  u16*   hb    = (u16*)(ws);                    // hidden bf16: 4096x2048
  u16*   wqkvT = (u16*)(ws + 16777216);         // [wq^T; wk^T; wv^T]: 2304x2048
  u16*   woT   = (u16*)(ws + 26214400);         // wo^T: 2048x2048
  float* bqkv  = (float*)(ws + 34603008);       // 2304 f32
  u16*   qkv   = (u16*)(ws + 34612224);         // 4096x2304 (Q cols pre-scaled by C_SL2)
  u16*   vt    = (u16*)(ws + 53486592);         // 2 x 128 x 2048
  u16*   attn  = (u16*)(ws + 54535168);         // 4096x2048

  k_prep<<<dim3(10377), dim3(256), 0, stream>>>(hidden, hb, wq, wk, wv, wqkvT,
                                                wo, woT, bq, bk, bv, bqkv);
  k_gemm<0><<<dim3(32, 18), dim3(256), 0, stream>>>(hb, wqkvT, bqkv, (void*)qkv, vt, 4096, NQKV, 2048);
  k_attn<<<dim3(64, 2, 2), dim3(512), 0, stream>>>(qkv, vt, mask, attn);
  k_gemm<1><<<dim3(32, 16), dim3(256), 0, stream>>>(attn, woT, bo, (void*)out, (u16*)nullptr, 4096, 2048, 2048);
}